// Round 2
// baseline (2123.852 us; speedup 1.0000x reference)
//
#include <hip/hip_runtime.h>
#include <hip/hip_bf16.h>

// ---------------------------------------------------------------------------
// UniPhyModel: B=1 T=8 C=4 IH=IW=256 P=16 -> HP=WP=16, D=256 (2D=512), L=2,
// NE=4, FF=1024.  Token layout everywhere: n = t*256 + hp*16 + wp (2048 tokens),
// channel c in [0,512): c<256 = real part, c>=256 = imag part.
// ---------------------------------------------------------------------------

#define TOKS 2048

enum GMode { MENC = 0, MCONV, MSQ, MMOE1, MMOE2, MDEC };

// Generic 64x64 tile fp32 GEMM, BK=16, 256 threads, 4x4 per thread.
// A is M x K (mode-specific gather), B is K x N row-major, C mode-specific.
template <int MODE>
__global__ __launch_bounds__(256) void gemm_k(
    const float* __restrict__ A, const float* __restrict__ B,
    const float* __restrict__ bias, const float* __restrict__ addv,
    const float* __restrict__ scalev, float* __restrict__ C, int K, int N) {
  __shared__ __align__(16) float As[16][68];
  __shared__ __align__(16) float Bs[16][68];
  const int tid = threadIdx.x;
  const int bm = blockIdx.x * 64;
  const int bn = blockIdx.y * 64;
  const int tx = tid & 15, ty = tid >> 4;
  float acc[4][4] = {};

  for (int k0 = 0; k0 < K; k0 += 16) {
    // ---- A tile: 64 rows x 16 k; each thread one float4 along K ----
    {
      const int row = tid >> 2;
      const int kc = (tid & 3) << 2;
      const int gm = bm + row;
      const int gk = k0 + kc;
      float4 av;
      if constexpr (MODE == MENC) {
        // A[n][k] = x[t, c, hp*16+ph, wp*16+pw]; k=(c,ph,pw)
        const int t = gm >> 8, hp = (gm >> 4) & 15, wp = gm & 15;
        const int c = gk >> 8, ph = (gk >> 4) & 15, pw = gk & 15;
        av = *(const float4*)&A[(((t * 4 + c) * 256 + hp * 16 + ph) << 8) +
                                wp * 16 + pw];
      } else if constexpr (MODE == MCONV) {
        // im2col: k = s*512 + ci, s=(kh,kw); neighbor pixel or zero-pad
        const int t = gm >> 8, h = (gm >> 4) & 15, w = gm & 15;
        const int s = gk >> 9, ci = gk & 511;
        const int kh = s / 3, kw = s - kh * 3;
        const int hh = h + kh - 1, ww = w + kw - 1;
        if (hh >= 0 && hh < 16 && ww >= 0 && ww < 16)
          av = *(const float4*)&A[(((t << 8) + hh * 16 + ww) << 9) + ci];
        else
          av = make_float4(0.f, 0.f, 0.f, 0.f);
      } else {
        av = *(const float4*)&A[(size_t)gm * K + gk];
      }
      As[kc + 0][row] = av.x;
      As[kc + 1][row] = av.y;
      As[kc + 2][row] = av.z;
      As[kc + 3][row] = av.w;
    }
    // ---- B tile: 16 k x 64 cols, coalesced ----
    {
      const int col = tid & 63;
      const int kb = tid >> 6;
#pragma unroll
      for (int i = 0; i < 4; i++) {
        const int gk = k0 + kb + (i << 2);
        Bs[kb + (i << 2)][col] = B[(size_t)gk * N + bn + col];
      }
    }
    __syncthreads();
#pragma unroll
    for (int kk = 0; kk < 16; kk++) {
      float4 a = *(const float4*)&As[kk][ty << 2];
      float4 b = *(const float4*)&Bs[kk][tx << 2];
      const float av4[4] = {a.x, a.y, a.z, a.w};
      const float bv4[4] = {b.x, b.y, b.z, b.w};
#pragma unroll
      for (int i = 0; i < 4; i++)
#pragma unroll
        for (int j = 0; j < 4; j++) acc[i][j] += av4[i] * bv4[j];
    }
    __syncthreads();
  }

#pragma unroll
  for (int i = 0; i < 4; i++) {
    const int gm = bm + (ty << 2) + i;
#pragma unroll
    for (int j = 0; j < 4; j++) {
      const int gn = bn + (tx << 2) + j;
      float v = acc[i][j];
      if constexpr (MODE == MENC) {
        C[gm * 512 + gn] = v + bias[gn];
      } else if constexpr (MODE == MCONV) {
        C[gm * 512 + gn] = v + bias[gn] + addv[gm * 512 + gn];
      } else if constexpr (MODE == MSQ) {
        C[gm * 512 + gn] = v;
      } else if constexpr (MODE == MMOE1) {
        // tanh-approx GELU (JAX default approximate=True)
        const float t = 0.7978845608028654f * (v + 0.044715f * v * v * v);
        C[(size_t)gm * 1024 + gn] = 0.5f * v * (1.f + tanhf(t));
      } else if constexpr (MODE == MMOE2) {
        C[gm * 512 + gn] += scalev[gm * 4] * v;
      } else {  // MDEC: scatter to (B,T,C,IH,IW)
        const int t = gm >> 8, hp = (gm >> 4) & 15, wp = gm & 15;
        const int c = gn >> 8, ph = (gn >> 4) & 15, pw = gn & 15;
        C[(((t * 4 + c) * 256 + hp * 16 + ph) << 8) + wp * 16 + pw] =
            v + bias[gn];
      }
    }
  }
}

// LayerNorm over 512 channels; one wave per token, 4 tokens per block.
__global__ __launch_bounds__(256) void ln_k(const float* __restrict__ in,
                                            const float* __restrict__ w,
                                            const float* __restrict__ b,
                                            float* __restrict__ out) {
  const int wv = threadIdx.x >> 6, lane = threadIdx.x & 63;
  const int n = (blockIdx.x << 2) + wv;
  const float* row = in + (size_t)n * 512;
  float v[8];
  float s = 0.f, s2 = 0.f;
#pragma unroll
  for (int i = 0; i < 8; i++) {
    const float x = row[(i << 6) + lane];
    v[i] = x;
    s += x;
    s2 += x * x;
  }
#pragma unroll
  for (int off = 32; off > 0; off >>= 1) {
    s += __shfl_down(s, off);
    s2 += __shfl_down(s2, off);
  }
  s = __shfl(s, 0);
  s2 = __shfl(s2, 0);
  const float m = s * (1.f / 512.f);
  const float var = s2 * (1.f / 512.f) - m * m;
  const float r = rsqrtf(var + 1e-5f);
#pragma unroll
  for (int i = 0; i < 8; i++) {
    const int c = (i << 6) + lane;
    out[(size_t)n * 512 + c] = (v[i] - m) * r * w[c] + b[c];
  }
}

// Transpose conv weights (512o,512i,3,3) -> Bt[k=s*512+ci][co], K=4608,N=512
__global__ __launch_bounds__(256) void convBt_k(const float* __restrict__ w,
                                                float* __restrict__ Bt) {
  const int idx = blockIdx.x * 256 + threadIdx.x;  // 4608*512
  const int k = idx >> 9;
  const int j = idx & 511;
  const int s = k >> 9;
  const int ci = k & 511;
  Bt[idx] = w[(size_t)(j * 512 + ci) * 9 + s];
}

// Build real 512x512 matrix [[Er, Ei], [-Ei, Er]] from complex 256x256 E.
__global__ __launch_bounds__(256) void build_M_k(const float* __restrict__ Er,
                                                 const float* __restrict__ Ei,
                                                 float* __restrict__ M) {
  const int idx = blockIdx.x * 256 + threadIdx.x;  // 512*512
  const int k = idx >> 9, j = idx & 511;
  const int kk = k & 255, jj = j & 255;
  const float er = Er[kk * 256 + jj], ei = Ei[kk * 256 + jj];
  float v;
  if (k < 256)
    v = (j < 256) ? er : ei;
  else
    v = (j < 256) ? -ei : er;
  M[idx] = v;
}

// Mean over 256 spatial positions: xm[t][c] = mean_p xe[(t,p)][c]
__global__ __launch_bounds__(256) void mean_k(const float* __restrict__ xe,
                                              float* __restrict__ xm) {
  const int t = blockIdx.x;
  const int c = blockIdx.y * 256 + threadIdx.x;
  float s = 0.f;
  for (int p = 0; p < 256; p++) s += xe[(size_t)((t << 8) + p) * 512 + c];
  xm[t * 512 + c] = s * (1.f / 256.f);
}

// Sequential flux scan over T=8 + lam/op_decay/op_forcing. One block, 256 thr.
__global__ __launch_bounds__(256) void flux_scan_k(
    const float* __restrict__ xm, const float* __restrict__ Wsr,
    const float* __restrict__ Wsi, const float* __restrict__ Wg,
    const float* __restrict__ bg, const float* __restrict__ lamre,
    const float* __restrict__ lamim, const float* __restrict__ dt,
    float* __restrict__ flux, float* __restrict__ srcs,
    float* __restrict__ gts, float* __restrict__ opd,
    float* __restrict__ opf) {
  const int d = threadIdx.x;  // 0..255
  __shared__ float sxm[512];
  float fr = flux[d], fi = flux[256 + d];
  const float lr0 = lamre[d];
  const float sp = (lr0 > 20.f) ? lr0 : log1pf(expf(lr0));
  const float lre = -(sp + 0.01f);
  const float lim = lamim[d];
  const float den = lre * lre + lim * lim;
  for (int t = 0; t < 8; t++) {
    for (int c = d; c < 512; c += 256) sxm[c] = xm[t * 512 + c];
    __syncthreads();
    float sr = 0.f, si = 0.f, ga = 0.f;
    for (int e = 0; e < 256; e++) {
      const float xr = sxm[e], xi = sxm[256 + e];
      const float wr = Wsr[e * 256 + d], wi = Wsi[e * 256 + d];
      sr += xr * wr - xi * wi;
      si += xr * wi + xi * wr;
    }
    for (int c = 0; c < 512; c++) ga += sxm[c] * Wg[c * 256 + d];
    const float g = 1.f / (1.f + expf(-(ga + bg[d])));
    fr = g * fr + (1.f - g) * sr;
    fi = g * fi + (1.f - g) * si;
    srcs[t * 512 + d] = sr;
    srcs[t * 512 + 256 + d] = si;
    gts[t * 256 + d] = g;
    const float dtv = dt[t];
    const float er = expf(lre * dtv);
    const float odr = er * cosf(lim * dtv);
    const float odi = er * sinf(lim * dtv);
    opd[t * 512 + d] = odr;
    opd[t * 512 + 256 + d] = odi;
    const float nr = odr - 1.f, ni = odi;
    opf[t * 512 + d] = (nr * lre + ni * lim) / den;
    opf[t * 512 + 256 + d] = (ni * lre - nr * lim) / den;
    __syncthreads();
  }
  flux[d] = fr;
  flux[256 + d] = fi;
}

// Per-(p,d) time scan: h[t] = u[t] + a[t]*h[t-1]; out[t] = h[t] + hprev*a[t]
__global__ __launch_bounds__(256) void time_scan_k(
    const float* __restrict__ xe, const float* __restrict__ gts,
    const float* __restrict__ srcs, const float* __restrict__ opd,
    const float* __restrict__ opf, float* __restrict__ hout,
    float* __restrict__ hprev) {
  const int d = threadIdx.x;
  const int p = blockIdx.x;
  float hr = 0.f, hi = 0.f;
  const float hpr = hprev[p * 512 + d], hpi = hprev[p * 512 + 256 + d];
  float o7r = 0.f, o7i = 0.f;
  for (int t = 0; t < 8; t++) {
    const size_t base = (size_t)((t << 8) + p) * 512;
    const float xr = xe[base + d], xi = xe[base + 256 + d];
    const float g = gts[t * 256 + d];
    const float sr = srcs[t * 512 + d], si = srcs[t * 512 + 256 + d];
    const float fr = xr * g + sr * (1.f - g);
    const float fi = xi * g + si * (1.f - g);
    const float ofr = opf[t * 512 + d], ofi = opf[t * 512 + 256 + d];
    const float ur = fr * ofr - fi * ofi;
    const float ui = fr * ofi + fi * ofr;
    const float ar = opd[t * 512 + d], ai = opd[t * 512 + 256 + d];
    const float nhr = ur + ar * hr - ai * hi;
    const float nhi = ui + ar * hi + ai * hr;
    hr = nhr;
    hi = nhi;
    const float outr = hr + ar * hpr - ai * hpi;
    const float outi = hi + ar * hpi + ai * hpr;
    hout[base + d] = outr;
    hout[base + 256 + d] = outi;
    if (t == 7) {
      o7r = outr;
      o7i = outi;
    }
  }
  hprev[p * 512 + d] = o7r;
  hprev[p * 512 + 256 + d] = o7i;
}

// probs = softmax(tok @ Wr) over 4 experts; one wave per token.
__global__ __launch_bounds__(64) void probs_k(const float* __restrict__ xn,
                                              const float* __restrict__ Wr,
                                              float* __restrict__ probs) {
  const int n = blockIdx.x;
  const int lane = threadIdx.x;
  float a0 = 0.f, a1 = 0.f, a2 = 0.f, a3 = 0.f;
  for (int c = lane; c < 512; c += 64) {
    const float x = xn[(size_t)n * 512 + c];
    a0 += x * Wr[c * 4 + 0];
    a1 += x * Wr[c * 4 + 1];
    a2 += x * Wr[c * 4 + 2];
    a3 += x * Wr[c * 4 + 3];
  }
#pragma unroll
  for (int off = 32; off > 0; off >>= 1) {
    a0 += __shfl_down(a0, off);
    a1 += __shfl_down(a1, off);
    a2 += __shfl_down(a2, off);
    a3 += __shfl_down(a3, off);
  }
  if (lane == 0) {
    float m = fmaxf(fmaxf(a0, a1), fmaxf(a2, a3));
    const float e0 = expf(a0 - m), e1 = expf(a1 - m), e2 = expf(a2 - m),
                e3 = expf(a3 - m);
    const float inv = 1.f / (e0 + e1 + e2 + e3);
    probs[n * 4 + 0] = e0 * inv;
    probs[n * 4 + 1] = e1 * inv;
    probs[n * 4 + 2] = e2 * inv;
    probs[n * 4 + 3] = e3 * inv;
  }
}

// z = x + xn + y (new block output / residual sum)
__global__ __launch_bounds__(256) void add3_k(const float* __restrict__ a,
                                              const float* __restrict__ b,
                                              const float* __restrict__ c,
                                              float* __restrict__ o) {
  const int i = blockIdx.x * 256 + threadIdx.x;
  o[i] = a[i] + b[i] + c[i];
}

extern "C" void kernel_launch(void* const* d_in, const int* in_sizes, int n_in,
                              void* d_out, int out_size, void* d_ws,
                              size_t ws_size, hipStream_t stream) {
  const float* x_in = (const float*)d_in[0];
  const float* dt = (const float*)d_in[1];
  const float* Wenc = (const float*)d_in[2];
  const float* benc = (const float*)d_in[3];
  const float* Wdec = (const float*)d_in[4];
  const float* bdec = (const float*)d_in[5];
  const float* ln_sp_w = (const float*)d_in[6];
  const float* ln_sp_b = (const float*)d_in[7];
  const float* conv_w = (const float*)d_in[8];
  const float* conv_b = (const float*)d_in[9];
  const float* E_re = (const float*)d_in[10];
  const float* E_im = (const float*)d_in[11];
  const float* Ed_re = (const float*)d_in[12];
  const float* Ed_im = (const float*)d_in[13];
  const float* Ws_re = (const float*)d_in[14];
  const float* Ws_im = (const float*)d_in[15];
  const float* Wg = (const float*)d_in[16];
  const float* bg = (const float*)d_in[17];
  const float* lam_re = (const float*)d_in[18];
  const float* lam_im = (const float*)d_in[19];
  const float* ln_t_w = (const float*)d_in[20];
  const float* ln_t_b = (const float*)d_in[21];
  const float* Wr = (const float*)d_in[22];
  const float* W1 = (const float*)d_in[23];
  const float* W2 = (const float*)d_in[24];
  float* out = (float*)d_out;

  float* ws = (float*)d_ws;
  size_t off = 0;
  auto alloc = [&](size_t n) {
    float* p = ws + off;
    off += n;
    return p;
  };
  float* z = alloc((size_t)TOKS * 512);
  float* zn = alloc((size_t)TOKS * 512);   // also reused as xn
  float* xb = alloc((size_t)TOKS * 512);   // x (post-conv residual)
  float* xe = alloc((size_t)TOKS * 512);   // x_eigen, then x_out
  float* hb = alloc((size_t)TOKS * 512);   // h
  float* yb = alloc((size_t)TOKS * 512);   // MoE y accumulator
  float* big = alloc((size_t)4608 * 512);  // union: conv Bt / MoE hid
  float* ME = alloc(512 * 512);
  float* MEd = alloc(512 * 512);
  float* hprev = alloc(256 * 512);
  float* flux = alloc(512);
  float* xm = alloc(8 * 512);
  float* srcs = alloc(8 * 512);
  float* gts = alloc(8 * 256);
  float* opd = alloc(8 * 512);
  float* opf = alloc(8 * 512);
  float* probs = alloc((size_t)TOKS * 4);

  // carried state starts at zero every call (ws is poisoned by harness)
  hipMemsetAsync(hprev, 0, 256 * 512 * sizeof(float), stream);
  hipMemsetAsync(flux, 0, 512 * sizeof(float), stream);

  // encoder: tokens(2048) x 1024 @ Wenc(1024x512) + benc
  gemm_k<MENC><<<dim3(32, 8), 256, 0, stream>>>(x_in, Wenc, benc, nullptr,
                                                nullptr, z, 1024, 512);

  for (int l = 0; l < 2; l++) {
    ln_k<<<512, 256, 0, stream>>>(z, ln_sp_w + l * 512, ln_sp_b + l * 512, zn);
    convBt_k<<<9216, 256, 0, stream>>>(conv_w + (size_t)l * 512 * 512 * 9, big);
    gemm_k<MCONV><<<dim3(32, 8), 256, 0, stream>>>(
        zn, big, conv_b + l * 512, z, nullptr, xb, 4608, 512);
    build_M_k<<<1024, 256, 0, stream>>>(E_re + l * 65536, E_im + l * 65536, ME);
    build_M_k<<<1024, 256, 0, stream>>>(Ed_re + l * 65536, Ed_im + l * 65536,
                                        MEd);
    gemm_k<MSQ><<<dim3(32, 8), 256, 0, stream>>>(xb, ME, nullptr, nullptr,
                                                 nullptr, xe, 512, 512);
    mean_k<<<dim3(8, 2), 256, 0, stream>>>(xe, xm);
    flux_scan_k<<<1, 256, 0, stream>>>(
        xm, Ws_re + l * 65536, Ws_im + l * 65536, Wg + l * 131072, bg + l * 256,
        lam_re + l * 256, lam_im + l * 256, dt, flux, srcs, gts, opd, opf);
    time_scan_k<<<256, 256, 0, stream>>>(xe, gts, srcs, opd, opf, hb, hprev);
    gemm_k<MSQ><<<dim3(32, 8), 256, 0, stream>>>(hb, MEd, nullptr, nullptr,
                                                 nullptr, xe, 512, 512);
    ln_k<<<512, 256, 0, stream>>>(xe, ln_t_w + l * 512, ln_t_b + l * 512, zn);
    probs_k<<<2048, 64, 0, stream>>>(zn, Wr + l * 2048, probs);
    hipMemsetAsync(yb, 0, (size_t)TOKS * 512 * sizeof(float), stream);
    for (int e = 0; e < 4; e++) {
      gemm_k<MMOE1><<<dim3(32, 16), 256, 0, stream>>>(
          zn, W1 + (size_t)(l * 4 + e) * 524288, nullptr, nullptr, nullptr, big,
          512, 1024);
      gemm_k<MMOE2><<<dim3(32, 8), 256, 0, stream>>>(
          big, W2 + (size_t)(l * 4 + e) * 524288, nullptr, nullptr, probs + e,
          yb, 1024, 512);
    }
    add3_k<<<4096, 256, 0, stream>>>(xb, zn, yb, z);
  }

  // decoder: tokens @ Wdec(512x1024) + bdec, scatter to (B,T,C,IH,IW)
  gemm_k<MDEC><<<dim3(32, 16), 256, 0, stream>>>(z, Wdec, bdec, nullptr,
                                                 nullptr, out, 512, 1024);
}

// Round 3
// 958.861 us; speedup vs baseline: 2.2150x; 2.2150x over previous
//
#include <hip/hip_runtime.h>
#include <hip/hip_bf16.h>

// ---------------------------------------------------------------------------
// UniPhyModel: B=1 T=8 C=4 IH=IW=256 P=16 -> HP=WP=16, D=256 (2D=512), L=2,
// NE=4, FF=1024.  Token n = t*256 + hp*16 + wp (2048 tokens), channel
// c in [0,512): c<256 real, c>=256 imag.  All GEMMs via bf16 MFMA 16x16x32,
// weights pre-transposed to Bt[n][k] bf16 once per launch.
// ---------------------------------------------------------------------------

#define TOKS 2048

typedef __bf16 bf16;
typedef __attribute__((ext_vector_type(8))) __bf16 bf16x8;
typedef __attribute__((ext_vector_type(4))) float f32x4;

enum GMode { EENC = 0, ECONV, ESQ, EMOE1, EMOE2, EDEC };

// MFMA GEMM: 64x64 tile / block, 256 thr = 4 waves, each wave 32x32 (2x2 frags)
// A: bf16 [M][K] row-major (ECONV: im2col halo gather from [2048][512]).
// Bt: bf16 [N][K] row-major.  K % 32 == 0.
template <int MODE>
__global__ __launch_bounds__(256) void mgemm_k(
    const bf16* __restrict__ A, const bf16* __restrict__ Bt,
    const float* __restrict__ bias, const float* __restrict__ addv,
    const float* __restrict__ scalev, float* __restrict__ C,
    bf16* __restrict__ C16, int K, int N) {
  __shared__ __align__(16) bf16 As[64 * 40];
  __shared__ __align__(16) bf16 Bs[64 * 40];
  const int tid = threadIdx.x;
  const int bm = blockIdx.x * 64, bn = blockIdx.y * 64;
  const int lane = tid & 63, w = tid >> 6;
  const int wm = (w & 1) * 32, wn = (w >> 1) * 32;
  const int quad = lane >> 4, l16 = lane & 15;
  const int srow = tid >> 2, sko = (tid & 3) << 3;  // staging: row, k-offset(8)

  f32x4 acc[2][2] = {};

  // precompute conv gather coords for the staging row
  int cv_t = 0, cv_h = 0, cv_w = 0;
  if constexpr (MODE == ECONV) {
    const int gm = bm + srow;
    cv_t = gm >> 8;
    cv_h = (gm >> 4) & 15;
    cv_w = gm & 15;
  }

  for (int k0 = 0; k0 < K; k0 += 32) {
    // ---- stage A (64 x 32) ----
    bf16x8 av;
    if constexpr (MODE == ECONV) {
      const int gk = k0 + sko;
      const int s = gk >> 9, ci = gk & 511;  // BK=32 divides 512 -> s uniform
      const int kh = s / 3, kw = s - kh * 3;
      const int hh = cv_h + kh - 1, ww = cv_w + kw - 1;
      if (hh >= 0 && hh < 16 && ww >= 0 && ww < 16) {
        av = *(const bf16x8*)&A[(size_t)(((cv_t << 8) + hh * 16 + ww) << 9) + ci];
      } else {
#pragma unroll
        for (int q = 0; q < 8; q++) av[q] = (bf16)0.0f;
      }
    } else {
      av = *(const bf16x8*)&A[(size_t)(bm + srow) * K + k0 + sko];
    }
    *(bf16x8*)&As[srow * 40 + sko] = av;
    // ---- stage Bt (64 x 32) ----
    *(bf16x8*)&Bs[srow * 40 + sko] =
        *(const bf16x8*)&Bt[(size_t)(bn + srow) * K + k0 + sko];
    __syncthreads();

    const bf16x8 a0 = *(const bf16x8*)&As[(wm + l16) * 40 + quad * 8];
    const bf16x8 a1 = *(const bf16x8*)&As[(wm + 16 + l16) * 40 + quad * 8];
    const bf16x8 b0 = *(const bf16x8*)&Bs[(wn + l16) * 40 + quad * 8];
    const bf16x8 b1 = *(const bf16x8*)&Bs[(wn + 16 + l16) * 40 + quad * 8];
    acc[0][0] = __builtin_amdgcn_mfma_f32_16x16x32_bf16(a0, b0, acc[0][0], 0, 0, 0);
    acc[0][1] = __builtin_amdgcn_mfma_f32_16x16x32_bf16(a0, b1, acc[0][1], 0, 0, 0);
    acc[1][0] = __builtin_amdgcn_mfma_f32_16x16x32_bf16(a1, b0, acc[1][0], 0, 0, 0);
    acc[1][1] = __builtin_amdgcn_mfma_f32_16x16x32_bf16(a1, b1, acc[1][1], 0, 0, 0);
    __syncthreads();
  }

  // ---- epilogue; C/D layout: col = lane&15, row = quad*4 + reg ----
#pragma unroll
  for (int i = 0; i < 2; i++) {
#pragma unroll
    for (int j = 0; j < 2; j++) {
#pragma unroll
      for (int r = 0; r < 4; r++) {
        const int gm = bm + wm + i * 16 + quad * 4 + r;
        const int gn = bn + wn + j * 16 + l16;
        const float v = acc[i][j][r];
        if constexpr (MODE == EENC) {
          C[(size_t)gm * 512 + gn] = v + bias[gn];
        } else if constexpr (MODE == ECONV) {
          const float o = v + bias[gn] + addv[(size_t)gm * 512 + gn];
          C[(size_t)gm * 512 + gn] = o;
          C16[(size_t)gm * 512 + gn] = (bf16)o;
        } else if constexpr (MODE == ESQ) {
          C[(size_t)gm * 512 + gn] = v;
        } else if constexpr (MODE == EMOE1) {
          const float t = 0.7978845608028654f * (v + 0.044715f * v * v * v);
          C16[(size_t)gm * 1024 + gn] = (bf16)(0.5f * v * (1.f + tanhf(t)));
        } else if constexpr (MODE == EMOE2) {
          C[(size_t)gm * 512 + gn] += scalev[gm * 4] * v;
        } else {  // EDEC scatter to (B,T,C,IH,IW)
          const int t = gm >> 8, hp = (gm >> 4) & 15, wp = gm & 15;
          const int c = gn >> 8, ph = (gn >> 4) & 15, pw = gn & 15;
          C[(size_t)(((t * 4 + c) * 256 + hp * 16 + ph) << 8) + wp * 16 + pw] =
              v + bias[gn];
        }
      }
    }
  }
}

// LayerNorm over 512 channels; writes fp32 + bf16.
__global__ __launch_bounds__(256) void ln_k(const float* __restrict__ in,
                                            const float* __restrict__ w,
                                            const float* __restrict__ b,
                                            float* __restrict__ out,
                                            bf16* __restrict__ out16) {
  const int wv = threadIdx.x >> 6, lane = threadIdx.x & 63;
  const int n = (blockIdx.x << 2) + wv;
  const float* row = in + (size_t)n * 512;
  float v[8];
  float s = 0.f, s2 = 0.f;
#pragma unroll
  for (int i = 0; i < 8; i++) {
    const float x = row[(i << 6) + lane];
    v[i] = x;
    s += x;
    s2 += x * x;
  }
#pragma unroll
  for (int off = 32; off > 0; off >>= 1) {
    s += __shfl_down(s, off);
    s2 += __shfl_down(s2, off);
  }
  s = __shfl(s, 0);
  s2 = __shfl(s2, 0);
  const float m = s * (1.f / 512.f);
  const float var = s2 * (1.f / 512.f) - m * m;
  const float r = rsqrtf(var + 1e-5f);
#pragma unroll
  for (int i = 0; i < 8; i++) {
    const int c = (i << 6) + lane;
    const float o = (v[i] - m) * r * w[c] + b[c];
    out[(size_t)n * 512 + c] = o;
    out16[(size_t)n * 512 + c] = (bf16)o;
  }
}

// x patches -> bf16 A_enc[n=2048][k=1024], k = c*256+ph*16+pw
__global__ __launch_bounds__(256) void cvt_enc_k(const float* __restrict__ x,
                                                 bf16* __restrict__ Ae) {
  const int id = blockIdx.x * 256 + threadIdx.x;  // 262144
  const int n = id >> 7;
  const int kc = (id & 127) << 3;
  const int t = n >> 8, hp = (n >> 4) & 15, wp = n & 15;
  const int c = kc >> 8, ph = (kc >> 4) & 15, pw = kc & 15;
  const float* src =
      &x[(size_t)(((t * 4 + c) * 256 + hp * 16 + ph) << 8) + wp * 16 + pw];
  const float4 v0 = *(const float4*)src;
  const float4 v1 = *(const float4*)(src + 4);
  bf16* d = &Ae[(size_t)n * 1024 + kc];
  d[0] = (bf16)v0.x; d[1] = (bf16)v0.y; d[2] = (bf16)v0.z; d[3] = (bf16)v0.w;
  d[4] = (bf16)v1.x; d[5] = (bf16)v1.y; d[6] = (bf16)v1.z; d[7] = (bf16)v1.w;
}

// fp32 [K][N] -> bf16 [N][K] tiled transpose; grid (K/32, N/32, batch)
__global__ __launch_bounds__(256) void cvtT_k(const float* __restrict__ src,
                                              bf16* __restrict__ dst, int K,
                                              int N) {
  __shared__ float tile[32][33];
  const size_t boff = (size_t)blockIdx.z * K * N;
  src += boff;
  dst += boff;
  const int k0 = blockIdx.x * 32, n0 = blockIdx.y * 32;
  const int tx = threadIdx.x & 31, ty = threadIdx.x >> 5;
#pragma unroll
  for (int r = 0; r < 4; r++)
    tile[ty + 8 * r][tx] = src[(size_t)(k0 + ty + 8 * r) * N + n0 + tx];
  __syncthreads();
#pragma unroll
  for (int r = 0; r < 4; r++)
    dst[(size_t)(n0 + ty + 8 * r) * K + k0 + tx] = (bf16)tile[tx][ty + 8 * r];
}

// Build bf16 MEt[z][j=512][k=512] = M[k][j], z = l*2 + (0:E, 1:Ed)
__global__ __launch_bounds__(256) void build_MEt_k(
    const float* __restrict__ E_re, const float* __restrict__ E_im,
    const float* __restrict__ Ed_re, const float* __restrict__ Ed_im,
    bf16* __restrict__ out) {
  const int z = blockIdx.z;
  const int l = z >> 1, which = z & 1;
  const float* Er = (which ? Ed_re : E_re) + l * 65536;
  const float* Ei = (which ? Ed_im : E_im) + l * 65536;
  bf16* dst = out + (size_t)z * 262144;
  const int idx = blockIdx.x * 256 + threadIdx.x;  // j*512+k
  const int j = idx >> 9, k = idx & 511;
  const int kk = k & 255, jj = j & 255;
  const float er = Er[kk * 256 + jj], ei = Ei[kk * 256 + jj];
  const float v = (k < 256) ? ((j < 256) ? er : ei) : ((j < 256) ? -ei : er);
  dst[idx] = (bf16)v;
}

// conv_w (O,I,3,3) -> bf16 Bt[l][co][k=s*512+ci]
__global__ __launch_bounds__(256) void convBt16_k(const float* __restrict__ w,
                                                  bf16* __restrict__ dst) {
  const int l = blockIdx.z;
  const float* src = w + (size_t)l * 512 * 512 * 9;
  bf16* d = dst + (size_t)l * 512 * 4608;
  const int idx = blockIdx.x * 256 + threadIdx.x;  // 2359296
  const int co = idx / 4608;
  const int rem = idx - co * 4608;
  const int s = rem >> 9, ci = rem & 511;
  d[idx] = (bf16)src[(size_t)(co * 512 + ci) * 9 + s];
}

// Mean over 256 spatial positions
__global__ __launch_bounds__(256) void mean_k(const float* __restrict__ xe,
                                              float* __restrict__ xm) {
  const int t = blockIdx.x;
  const int c = blockIdx.y * 256 + threadIdx.x;
  float s = 0.f;
  for (int p = 0; p < 256; p++) s += xe[(size_t)((t << 8) + p) * 512 + c];
  xm[t * 512 + c] = s * (1.f / 256.f);
}

// Sequential flux scan over T=8 + lam/op_decay/op_forcing.
__global__ __launch_bounds__(256) void flux_scan_k(
    const float* __restrict__ xm, const float* __restrict__ Wsr,
    const float* __restrict__ Wsi, const float* __restrict__ Wg,
    const float* __restrict__ bg, const float* __restrict__ lamre,
    const float* __restrict__ lamim, const float* __restrict__ dt,
    float* __restrict__ flux, float* __restrict__ srcs, float* __restrict__ gts,
    float* __restrict__ opd, float* __restrict__ opf) {
  const int d = threadIdx.x;
  __shared__ float sxm[512];
  float fr = flux[d], fi = flux[256 + d];
  const float lr0 = lamre[d];
  const float sp = (lr0 > 20.f) ? lr0 : log1pf(expf(lr0));
  const float lre = -(sp + 0.01f);
  const float lim = lamim[d];
  const float den = lre * lre + lim * lim;
  for (int t = 0; t < 8; t++) {
    for (int c = d; c < 512; c += 256) sxm[c] = xm[t * 512 + c];
    __syncthreads();
    float sr = 0.f, si = 0.f, ga = 0.f;
    for (int e = 0; e < 256; e++) {
      const float xr = sxm[e], xi = sxm[256 + e];
      const float wr = Wsr[e * 256 + d], wi = Wsi[e * 256 + d];
      sr += xr * wr - xi * wi;
      si += xr * wi + xi * wr;
    }
    for (int c = 0; c < 512; c++) ga += sxm[c] * Wg[c * 256 + d];
    const float g = 1.f / (1.f + expf(-(ga + bg[d])));
    fr = g * fr + (1.f - g) * sr;
    fi = g * fi + (1.f - g) * si;
    srcs[t * 512 + d] = sr;
    srcs[t * 512 + 256 + d] = si;
    gts[t * 256 + d] = g;
    const float dtv = dt[t];
    const float er = expf(lre * dtv);
    const float odr = er * cosf(lim * dtv);
    const float odi = er * sinf(lim * dtv);
    opd[t * 512 + d] = odr;
    opd[t * 512 + 256 + d] = odi;
    const float nr = odr - 1.f, ni = odi;
    opf[t * 512 + d] = (nr * lre + ni * lim) / den;
    opf[t * 512 + 256 + d] = (ni * lre - nr * lim) / den;
    __syncthreads();
  }
  flux[d] = fr;
  flux[256 + d] = fi;
}

// Per-(p,d) time scan -> bf16 h, updates fp32 hprev
__global__ __launch_bounds__(256) void time_scan_k(
    const float* __restrict__ xe, const float* __restrict__ gts,
    const float* __restrict__ srcs, const float* __restrict__ opd,
    const float* __restrict__ opf, bf16* __restrict__ hout16,
    float* __restrict__ hprev) {
  const int d = threadIdx.x;
  const int p = blockIdx.x;
  float hr = 0.f, hi = 0.f;
  const float hpr = hprev[p * 512 + d], hpi = hprev[p * 512 + 256 + d];
  float o7r = 0.f, o7i = 0.f;
  for (int t = 0; t < 8; t++) {
    const size_t base = (size_t)((t << 8) + p) * 512;
    const float xr = xe[base + d], xi = xe[base + 256 + d];
    const float g = gts[t * 256 + d];
    const float sr = srcs[t * 512 + d], si = srcs[t * 512 + 256 + d];
    const float fr = xr * g + sr * (1.f - g);
    const float fi = xi * g + si * (1.f - g);
    const float ofr = opf[t * 512 + d], ofi = opf[t * 512 + 256 + d];
    const float ur = fr * ofr - fi * ofi;
    const float ui = fr * ofi + fi * ofr;
    const float ar = opd[t * 512 + d], ai = opd[t * 512 + 256 + d];
    const float nhr = ur + ar * hr - ai * hi;
    const float nhi = ui + ar * hi + ai * hr;
    hr = nhr;
    hi = nhi;
    const float outr = hr + ar * hpr - ai * hpi;
    const float outi = hi + ar * hpi + ai * hpr;
    hout16[base + d] = (bf16)outr;
    hout16[base + 256 + d] = (bf16)outi;
    if (t == 7) {
      o7r = outr;
      o7i = outi;
    }
  }
  hprev[p * 512 + d] = o7r;
  hprev[p * 512 + 256 + d] = o7i;
}

// probs = softmax(tok @ Wr) over 4 experts; one wave per token.
__global__ __launch_bounds__(64) void probs_k(const float* __restrict__ xn,
                                              const float* __restrict__ Wr,
                                              float* __restrict__ probs) {
  const int n = blockIdx.x;
  const int lane = threadIdx.x;
  float a0 = 0.f, a1 = 0.f, a2 = 0.f, a3 = 0.f;
  for (int c = lane; c < 512; c += 64) {
    const float x = xn[(size_t)n * 512 + c];
    a0 += x * Wr[c * 4 + 0];
    a1 += x * Wr[c * 4 + 1];
    a2 += x * Wr[c * 4 + 2];
    a3 += x * Wr[c * 4 + 3];
  }
#pragma unroll
  for (int off = 32; off > 0; off >>= 1) {
    a0 += __shfl_down(a0, off);
    a1 += __shfl_down(a1, off);
    a2 += __shfl_down(a2, off);
    a3 += __shfl_down(a3, off);
  }
  if (lane == 0) {
    float m = fmaxf(fmaxf(a0, a1), fmaxf(a2, a3));
    const float e0 = expf(a0 - m), e1 = expf(a1 - m), e2 = expf(a2 - m),
                e3 = expf(a3 - m);
    const float inv = 1.f / (e0 + e1 + e2 + e3);
    probs[n * 4 + 0] = e0 * inv;
    probs[n * 4 + 1] = e1 * inv;
    probs[n * 4 + 2] = e2 * inv;
    probs[n * 4 + 3] = e3 * inv;
  }
}

// z = a + b + c (fp32) + bf16 copy
__global__ __launch_bounds__(256) void add3_k(const float* __restrict__ a,
                                              const float* __restrict__ b,
                                              const float* __restrict__ c,
                                              float* __restrict__ o,
                                              bf16* __restrict__ o16) {
  const int i = blockIdx.x * 256 + threadIdx.x;
  const float v = a[i] + b[i] + c[i];
  o[i] = v;
  o16[i] = (bf16)v;
}

extern "C" void kernel_launch(void* const* d_in, const int* in_sizes, int n_in,
                              void* d_out, int out_size, void* d_ws,
                              size_t ws_size, hipStream_t stream) {
  const float* x_in = (const float*)d_in[0];
  const float* dt = (const float*)d_in[1];
  const float* Wenc = (const float*)d_in[2];
  const float* benc = (const float*)d_in[3];
  const float* Wdec = (const float*)d_in[4];
  const float* bdec = (const float*)d_in[5];
  const float* ln_sp_w = (const float*)d_in[6];
  const float* ln_sp_b = (const float*)d_in[7];
  const float* conv_w = (const float*)d_in[8];
  const float* conv_b = (const float*)d_in[9];
  const float* E_re = (const float*)d_in[10];
  const float* E_im = (const float*)d_in[11];
  const float* Ed_re = (const float*)d_in[12];
  const float* Ed_im = (const float*)d_in[13];
  const float* Ws_re = (const float*)d_in[14];
  const float* Ws_im = (const float*)d_in[15];
  const float* Wg = (const float*)d_in[16];
  const float* bg = (const float*)d_in[17];
  const float* lam_re = (const float*)d_in[18];
  const float* lam_im = (const float*)d_in[19];
  const float* ln_t_w = (const float*)d_in[20];
  const float* ln_t_b = (const float*)d_in[21];
  const float* Wr = (const float*)d_in[22];
  const float* W1 = (const float*)d_in[23];
  const float* W2 = (const float*)d_in[24];
  float* out = (float*)d_out;

  float* ws = (float*)d_ws;
  size_t off = 0;
  auto allocf = [&](size_t n) {
    float* p = ws + off;
    off += n;
    return p;
  };
  auto allocb = [&](size_t n) {  // n bf16 elements (n even)
    bf16* p = (bf16*)(ws + off);
    off += n / 2;
    return p;
  };
  // fp32 buffers
  float* z = allocf((size_t)TOKS * 512);
  float* zn = allocf((size_t)TOKS * 512);
  float* xb = allocf((size_t)TOKS * 512);
  float* xe = allocf((size_t)TOKS * 512);
  float* yb = allocf((size_t)TOKS * 512);
  float* hprev = allocf(256 * 512);
  float* flux = allocf(512);
  float* xm = allocf(8 * 512);
  float* srcs = allocf(8 * 512);
  float* gts = allocf(8 * 256);
  float* opd = allocf(8 * 512);
  float* opf = allocf(8 * 512);
  float* probs = allocf((size_t)TOKS * 4);
  // bf16 buffers
  bf16* zn16 = allocb((size_t)TOKS * 512);
  bf16* xb16 = allocb((size_t)TOKS * 512);
  bf16* z16 = allocb((size_t)TOKS * 512);
  bf16* hb16 = allocb((size_t)TOKS * 512);
  bf16* hid16 = allocb((size_t)TOKS * 1024);
  bf16* Aenc16 = allocb((size_t)TOKS * 1024);
  bf16* WencT = allocb((size_t)512 * 1024);
  bf16* WdecT = allocb((size_t)1024 * 512);
  bf16* MEt = allocb((size_t)4 * 512 * 512);
  bf16* convBt = allocb((size_t)2 * 512 * 4608);
  bf16* W1T = allocb((size_t)8 * 1024 * 512);
  bf16* W2T = allocb((size_t)8 * 512 * 1024);

  hipMemsetAsync(hprev, 0, 256 * 512 * sizeof(float), stream);
  hipMemsetAsync(flux, 0, 512 * sizeof(float), stream);

  // ---- weight / input conversions (once per launch) ----
  cvt_enc_k<<<1024, 256, 0, stream>>>(x_in, Aenc16);
  cvtT_k<<<dim3(32, 16, 1), 256, 0, stream>>>(Wenc, WencT, 1024, 512);
  cvtT_k<<<dim3(16, 32, 1), 256, 0, stream>>>(Wdec, WdecT, 512, 1024);
  cvtT_k<<<dim3(16, 32, 8), 256, 0, stream>>>(W1, W1T, 512, 1024);
  cvtT_k<<<dim3(32, 16, 8), 256, 0, stream>>>(W2, W2T, 1024, 512);
  build_MEt_k<<<dim3(1024, 1, 4), 256, 0, stream>>>(E_re, E_im, Ed_re, Ed_im,
                                                    MEt);
  convBt16_k<<<dim3(9216, 1, 2), 256, 0, stream>>>(conv_w, convBt);

  // ---- encoder ----
  mgemm_k<EENC><<<dim3(32, 8), 256, 0, stream>>>(Aenc16, WencT, benc, nullptr,
                                                 nullptr, z, nullptr, 1024, 512);

  for (int l = 0; l < 2; l++) {
    ln_k<<<512, 256, 0, stream>>>(z, ln_sp_w + l * 512, ln_sp_b + l * 512, zn,
                                  zn16);
    mgemm_k<ECONV><<<dim3(32, 8), 256, 0, stream>>>(
        zn16, convBt + (size_t)l * 512 * 4608, conv_b + l * 512, z, nullptr, xb,
        xb16, 4608, 512);
    mgemm_k<ESQ><<<dim3(32, 8), 256, 0, stream>>>(
        xb16, MEt + (size_t)(l * 2) * 262144, nullptr, nullptr, nullptr, xe,
        nullptr, 512, 512);
    mean_k<<<dim3(8, 2), 256, 0, stream>>>(xe, xm);
    flux_scan_k<<<1, 256, 0, stream>>>(
        xm, Ws_re + l * 65536, Ws_im + l * 65536, Wg + l * 131072, bg + l * 256,
        lam_re + l * 256, lam_im + l * 256, dt, flux, srcs, gts, opd, opf);
    time_scan_k<<<256, 256, 0, stream>>>(xe, gts, srcs, opd, opf, hb16, hprev);
    mgemm_k<ESQ><<<dim3(32, 8), 256, 0, stream>>>(
        hb16, MEt + (size_t)(l * 2 + 1) * 262144, nullptr, nullptr, nullptr, xe,
        nullptr, 512, 512);
    ln_k<<<512, 256, 0, stream>>>(xe, ln_t_w + l * 512, ln_t_b + l * 512, zn,
                                  zn16);
    probs_k<<<2048, 64, 0, stream>>>(zn, Wr + l * 2048, probs);
    hipMemsetAsync(yb, 0, (size_t)TOKS * 512 * sizeof(float), stream);
    for (int e = 0; e < 4; e++) {
      mgemm_k<EMOE1><<<dim3(32, 16), 256, 0, stream>>>(
          zn16, W1T + (size_t)(l * 4 + e) * 524288, nullptr, nullptr, nullptr,
          nullptr, hid16, 512, 1024);
      mgemm_k<EMOE2><<<dim3(32, 8), 256, 0, stream>>>(
          hid16, W2T + (size_t)(l * 4 + e) * 524288, nullptr, nullptr,
          probs + e, yb, nullptr, 1024, 512);
    }
    add3_k<<<4096, 256, 0, stream>>>(xb, zn, yb, z, z16);
  }

  // ---- decoder ----
  mgemm_k<EDEC><<<dim3(32, 16), 256, 0, stream>>>(z16, WdecT, bdec, nullptr,
                                                  nullptr, out, nullptr, 512,
                                                  1024);
}

// Round 4
// 722.542 us; speedup vs baseline: 2.9394x; 1.3271x over previous
//
#include <hip/hip_runtime.h>
#include <hip/hip_bf16.h>

// ---------------------------------------------------------------------------
// UniPhyModel: B=1 T=8 C=4 IH=IW=256 P=16 -> HP=WP=16, D=256 (2D=512), L=2,
// NE=4, FF=1024.  Token n = t*256 + hp*16 + wp (2048 tokens), channel
// c in [0,512): c<256 real, c>=256 imag.  All GEMMs via bf16 MFMA 16x16x32.
// Flux scan split: parallel src/gate (no flux dep) + tiny sequential rec.
// ---------------------------------------------------------------------------

#define TOKS 2048

typedef __bf16 bf16;
typedef __attribute__((ext_vector_type(8))) __bf16 bf16x8;
typedef __attribute__((ext_vector_type(4))) float f32x4;

enum GMode { EENC = 0, ECONV, ESQ, EMOE1, EMOE2, EDEC };

// MFMA GEMM: 64x64 tile / block, 256 thr = 4 waves, each wave 32x32 (2x2 frags)
template <int MODE>
__global__ __launch_bounds__(256) void mgemm_k(
    const bf16* __restrict__ A, const bf16* __restrict__ Bt,
    const float* __restrict__ bias, const float* __restrict__ addv,
    const float* __restrict__ scalev, float* __restrict__ C,
    bf16* __restrict__ C16, int K, int N) {
  __shared__ __align__(16) bf16 As[64 * 40];
  __shared__ __align__(16) bf16 Bs[64 * 40];
  const int tid = threadIdx.x;
  const int bm = blockIdx.x * 64, bn = blockIdx.y * 64;
  const int lane = tid & 63, w = tid >> 6;
  const int wm = (w & 1) * 32, wn = (w >> 1) * 32;
  const int quad = lane >> 4, l16 = lane & 15;
  const int srow = tid >> 2, sko = (tid & 3) << 3;

  f32x4 acc[2][2] = {};

  int cv_t = 0, cv_h = 0, cv_w = 0;
  if constexpr (MODE == ECONV) {
    const int gm = bm + srow;
    cv_t = gm >> 8;
    cv_h = (gm >> 4) & 15;
    cv_w = gm & 15;
  }

  for (int k0 = 0; k0 < K; k0 += 32) {
    bf16x8 av;
    if constexpr (MODE == ECONV) {
      const int gk = k0 + sko;
      const int s = gk >> 9, ci = gk & 511;
      const int kh = s / 3, kw = s - kh * 3;
      const int hh = cv_h + kh - 1, ww = cv_w + kw - 1;
      if (hh >= 0 && hh < 16 && ww >= 0 && ww < 16) {
        av = *(const bf16x8*)&A[(size_t)(((cv_t << 8) + hh * 16 + ww) << 9) + ci];
      } else {
#pragma unroll
        for (int q = 0; q < 8; q++) av[q] = (bf16)0.0f;
      }
    } else {
      av = *(const bf16x8*)&A[(size_t)(bm + srow) * K + k0 + sko];
    }
    *(bf16x8*)&As[srow * 40 + sko] = av;
    *(bf16x8*)&Bs[srow * 40 + sko] =
        *(const bf16x8*)&Bt[(size_t)(bn + srow) * K + k0 + sko];
    __syncthreads();

    const bf16x8 a0 = *(const bf16x8*)&As[(wm + l16) * 40 + quad * 8];
    const bf16x8 a1 = *(const bf16x8*)&As[(wm + 16 + l16) * 40 + quad * 8];
    const bf16x8 b0 = *(const bf16x8*)&Bs[(wn + l16) * 40 + quad * 8];
    const bf16x8 b1 = *(const bf16x8*)&Bs[(wn + 16 + l16) * 40 + quad * 8];
    acc[0][0] = __builtin_amdgcn_mfma_f32_16x16x32_bf16(a0, b0, acc[0][0], 0, 0, 0);
    acc[0][1] = __builtin_amdgcn_mfma_f32_16x16x32_bf16(a0, b1, acc[0][1], 0, 0, 0);
    acc[1][0] = __builtin_amdgcn_mfma_f32_16x16x32_bf16(a1, b0, acc[1][0], 0, 0, 0);
    acc[1][1] = __builtin_amdgcn_mfma_f32_16x16x32_bf16(a1, b1, acc[1][1], 0, 0, 0);
    __syncthreads();
  }

#pragma unroll
  for (int i = 0; i < 2; i++) {
#pragma unroll
    for (int j = 0; j < 2; j++) {
#pragma unroll
      for (int r = 0; r < 4; r++) {
        const int gm = bm + wm + i * 16 + quad * 4 + r;
        const int gn = bn + wn + j * 16 + l16;
        const float v = acc[i][j][r];
        if constexpr (MODE == EENC) {
          C[(size_t)gm * 512 + gn] = v + bias[gn];
        } else if constexpr (MODE == ECONV) {
          const float o = v + bias[gn] + addv[(size_t)gm * 512 + gn];
          C[(size_t)gm * 512 + gn] = o;
          C16[(size_t)gm * 512 + gn] = (bf16)o;
        } else if constexpr (MODE == ESQ) {
          C[(size_t)gm * 512 + gn] = v;
        } else if constexpr (MODE == EMOE1) {
          const float t = 0.7978845608028654f * (v + 0.044715f * v * v * v);
          C16[(size_t)gm * 1024 + gn] = (bf16)(0.5f * v * (1.f + tanhf(t)));
        } else if constexpr (MODE == EMOE2) {
          C[(size_t)gm * 512 + gn] += scalev[gm * 4] * v;
        } else {  // EDEC
          const int t = gm >> 8, hp = (gm >> 4) & 15, wp = gm & 15;
          const int c = gn >> 8, ph = (gn >> 4) & 15, pw = gn & 15;
          C[(size_t)(((t * 4 + c) * 256 + hp * 16 + ph) << 8) + wp * 16 + pw] =
              v + bias[gn];
        }
      }
    }
  }
}

// LayerNorm over 512 channels; writes fp32 + bf16.
__global__ __launch_bounds__(256) void ln_k(const float* __restrict__ in,
                                            const float* __restrict__ w,
                                            const float* __restrict__ b,
                                            float* __restrict__ out,
                                            bf16* __restrict__ out16) {
  const int wv = threadIdx.x >> 6, lane = threadIdx.x & 63;
  const int n = (blockIdx.x << 2) + wv;
  const float* row = in + (size_t)n * 512;
  float v[8];
  float s = 0.f, s2 = 0.f;
#pragma unroll
  for (int i = 0; i < 8; i++) {
    const float x = row[(i << 6) + lane];
    v[i] = x;
    s += x;
    s2 += x * x;
  }
#pragma unroll
  for (int off = 32; off > 0; off >>= 1) {
    s += __shfl_down(s, off);
    s2 += __shfl_down(s2, off);
  }
  s = __shfl(s, 0);
  s2 = __shfl(s2, 0);
  const float m = s * (1.f / 512.f);
  const float var = s2 * (1.f / 512.f) - m * m;
  const float r = rsqrtf(var + 1e-5f);
#pragma unroll
  for (int i = 0; i < 8; i++) {
    const int c = (i << 6) + lane;
    const float o = (v[i] - m) * r * w[c] + b[c];
    out[(size_t)n * 512 + c] = o;
    out16[(size_t)n * 512 + c] = (bf16)o;
  }
}

// x patches -> bf16 A_enc[n=2048][k=1024]
__global__ __launch_bounds__(256) void cvt_enc_k(const float* __restrict__ x,
                                                 bf16* __restrict__ Ae) {
  const int id = blockIdx.x * 256 + threadIdx.x;
  const int n = id >> 7;
  const int kc = (id & 127) << 3;
  const int t = n >> 8, hp = (n >> 4) & 15, wp = n & 15;
  const int c = kc >> 8, ph = (kc >> 4) & 15, pw = kc & 15;
  const float* src =
      &x[(size_t)(((t * 4 + c) * 256 + hp * 16 + ph) << 8) + wp * 16 + pw];
  const float4 v0 = *(const float4*)src;
  const float4 v1 = *(const float4*)(src + 4);
  bf16* d = &Ae[(size_t)n * 1024 + kc];
  d[0] = (bf16)v0.x; d[1] = (bf16)v0.y; d[2] = (bf16)v0.z; d[3] = (bf16)v0.w;
  d[4] = (bf16)v1.x; d[5] = (bf16)v1.y; d[6] = (bf16)v1.z; d[7] = (bf16)v1.w;
}

// fp32 [K][N] -> bf16 [N][K] tiled transpose; grid (K/32, N/32, batch)
__global__ __launch_bounds__(256) void cvtT_k(const float* __restrict__ src,
                                              bf16* __restrict__ dst, int K,
                                              int N) {
  __shared__ float tile[32][33];
  const size_t boff = (size_t)blockIdx.z * K * N;
  src += boff;
  dst += boff;
  const int k0 = blockIdx.x * 32, n0 = blockIdx.y * 32;
  const int tx = threadIdx.x & 31, ty = threadIdx.x >> 5;
#pragma unroll
  for (int r = 0; r < 4; r++)
    tile[ty + 8 * r][tx] = src[(size_t)(k0 + ty + 8 * r) * N + n0 + tx];
  __syncthreads();
#pragma unroll
  for (int r = 0; r < 4; r++)
    dst[(size_t)(n0 + ty + 8 * r) * K + k0 + tx] = (bf16)tile[tx][ty + 8 * r];
}

// Build bf16 MEt[z][j=512][k=512] = M[k][j]
__global__ __launch_bounds__(256) void build_MEt_k(
    const float* __restrict__ E_re, const float* __restrict__ E_im,
    const float* __restrict__ Ed_re, const float* __restrict__ Ed_im,
    bf16* __restrict__ out) {
  const int z = blockIdx.z;
  const int l = z >> 1, which = z & 1;
  const float* Er = (which ? Ed_re : E_re) + l * 65536;
  const float* Ei = (which ? Ed_im : E_im) + l * 65536;
  bf16* dst = out + (size_t)z * 262144;
  const int idx = blockIdx.x * 256 + threadIdx.x;
  const int j = idx >> 9, k = idx & 511;
  const int kk = k & 255, jj = j & 255;
  const float er = Er[kk * 256 + jj], ei = Ei[kk * 256 + jj];
  const float v = (k < 256) ? ((j < 256) ? er : ei) : ((j < 256) ? -ei : er);
  dst[idx] = (bf16)v;
}

// conv_w (O,I,3,3) -> bf16 Bt[l][co][k=s*512+ci]
__global__ __launch_bounds__(256) void convBt16_k(const float* __restrict__ w,
                                                  bf16* __restrict__ dst) {
  const int l = blockIdx.z;
  const float* src = w + (size_t)l * 512 * 512 * 9;
  bf16* d = dst + (size_t)l * 512 * 4608;
  const int idx = blockIdx.x * 256 + threadIdx.x;
  const int co = idx / 4608;
  const int rem = idx - co * 4608;
  const int s = rem >> 9, ci = rem & 511;
  d[idx] = (bf16)src[(size_t)(co * 512 + ci) * 9 + s];
}

// Mean over 256 spatial positions
__global__ __launch_bounds__(256) void mean_k(const float* __restrict__ xe,
                                              float* __restrict__ xm) {
  const int t = blockIdx.x;
  const int c = blockIdx.y * 256 + threadIdx.x;
  float s = 0.f;
  for (int p = 0; p < 256; p++) s += xe[(size_t)((t << 8) + p) * 512 + c];
  xm[t * 512 + c] = s * (1.f / 256.f);
}

// Parallel src/gate over all t (no flux dependency).
// grid (8 t, 3 part) x 256 thr. part 0: src.re, 1: src.im, 2: gate.
__global__ __launch_bounds__(256) void srcgate_k(
    const float* __restrict__ xm, const float* __restrict__ Wsr,
    const float* __restrict__ Wsi, const float* __restrict__ Wg,
    const float* __restrict__ bg, float* __restrict__ srcs,
    float* __restrict__ gts) {
  const int t = blockIdx.x, part = blockIdx.y, d = threadIdx.x;
  __shared__ float sxm[512];
  for (int c = d; c < 512; c += 256) sxm[c] = xm[t * 512 + c];
  __syncthreads();
  if (part == 0) {
    float s0 = 0.f, s1 = 0.f, s2 = 0.f, s3 = 0.f;
#pragma unroll 4
    for (int e = 0; e < 256; e += 4) {
      s0 += sxm[e + 0] * Wsr[(e + 0) * 256 + d] - sxm[256 + e + 0] * Wsi[(e + 0) * 256 + d];
      s1 += sxm[e + 1] * Wsr[(e + 1) * 256 + d] - sxm[256 + e + 1] * Wsi[(e + 1) * 256 + d];
      s2 += sxm[e + 2] * Wsr[(e + 2) * 256 + d] - sxm[256 + e + 2] * Wsi[(e + 2) * 256 + d];
      s3 += sxm[e + 3] * Wsr[(e + 3) * 256 + d] - sxm[256 + e + 3] * Wsi[(e + 3) * 256 + d];
    }
    srcs[t * 512 + d] = (s0 + s1) + (s2 + s3);
  } else if (part == 1) {
    float s0 = 0.f, s1 = 0.f, s2 = 0.f, s3 = 0.f;
#pragma unroll 4
    for (int e = 0; e < 256; e += 4) {
      s0 += sxm[e + 0] * Wsi[(e + 0) * 256 + d] + sxm[256 + e + 0] * Wsr[(e + 0) * 256 + d];
      s1 += sxm[e + 1] * Wsi[(e + 1) * 256 + d] + sxm[256 + e + 1] * Wsr[(e + 1) * 256 + d];
      s2 += sxm[e + 2] * Wsi[(e + 2) * 256 + d] + sxm[256 + e + 2] * Wsr[(e + 2) * 256 + d];
      s3 += sxm[e + 3] * Wsi[(e + 3) * 256 + d] + sxm[256 + e + 3] * Wsr[(e + 3) * 256 + d];
    }
    srcs[t * 512 + 256 + d] = (s0 + s1) + (s2 + s3);
  } else {
    float s0 = 0.f, s1 = 0.f, s2 = 0.f, s3 = 0.f;
#pragma unroll 4
    for (int c = 0; c < 512; c += 4) {
      s0 += sxm[c + 0] * Wg[(c + 0) * 256 + d];
      s1 += sxm[c + 1] * Wg[(c + 1) * 256 + d];
      s2 += sxm[c + 2] * Wg[(c + 2) * 256 + d];
      s3 += sxm[c + 3] * Wg[(c + 3) * 256 + d];
    }
    const float ga = (s0 + s1) + (s2 + s3) + bg[d];
    gts[t * 256 + d] = 1.f / (1.f + expf(-ga));
  }
}

// Tiny sequential flux recurrence + opd/opf; one block, 256 threads.
__global__ __launch_bounds__(256) void fluxrec_k(
    const float* __restrict__ srcs, const float* __restrict__ gts,
    const float* __restrict__ lamre, const float* __restrict__ lamim,
    const float* __restrict__ dt, float* __restrict__ flux,
    float* __restrict__ opd, float* __restrict__ opf) {
  const int d = threadIdx.x;
  float fr = flux[d], fi = flux[256 + d];
  const float lr0 = lamre[d];
  const float sp = (lr0 > 20.f) ? lr0 : log1pf(expf(lr0));
  const float lre = -(sp + 0.01f);
  const float lim = lamim[d];
  const float den = lre * lre + lim * lim;
#pragma unroll
  for (int t = 0; t < 8; t++) {
    const float g = gts[t * 256 + d];
    const float sr = srcs[t * 512 + d], si = srcs[t * 512 + 256 + d];
    fr = g * fr + (1.f - g) * sr;
    fi = g * fi + (1.f - g) * si;
    const float dtv = dt[t];
    const float er = expf(lre * dtv);
    const float odr = er * cosf(lim * dtv);
    const float odi = er * sinf(lim * dtv);
    opd[t * 512 + d] = odr;
    opd[t * 512 + 256 + d] = odi;
    const float nr = odr - 1.f, ni = odi;
    opf[t * 512 + d] = (nr * lre + ni * lim) / den;
    opf[t * 512 + 256 + d] = (ni * lre - nr * lim) / den;
  }
  flux[d] = fr;
  flux[256 + d] = fi;
}

// Per-(p,d) time scan -> bf16 h, updates fp32 hprev
__global__ __launch_bounds__(256) void time_scan_k(
    const float* __restrict__ xe, const float* __restrict__ gts,
    const float* __restrict__ srcs, const float* __restrict__ opd,
    const float* __restrict__ opf, bf16* __restrict__ hout16,
    float* __restrict__ hprev) {
  const int d = threadIdx.x;
  const int p = blockIdx.x;
  float hr = 0.f, hi = 0.f;
  const float hpr = hprev[p * 512 + d], hpi = hprev[p * 512 + 256 + d];
  float o7r = 0.f, o7i = 0.f;
  for (int t = 0; t < 8; t++) {
    const size_t base = (size_t)((t << 8) + p) * 512;
    const float xr = xe[base + d], xi = xe[base + 256 + d];
    const float g = gts[t * 256 + d];
    const float sr = srcs[t * 512 + d], si = srcs[t * 512 + 256 + d];
    const float fr = xr * g + sr * (1.f - g);
    const float fi = xi * g + si * (1.f - g);
    const float ofr = opf[t * 512 + d], ofi = opf[t * 512 + 256 + d];
    const float ur = fr * ofr - fi * ofi;
    const float ui = fr * ofi + fi * ofr;
    const float ar = opd[t * 512 + d], ai = opd[t * 512 + 256 + d];
    const float nhr = ur + ar * hr - ai * hi;
    const float nhi = ui + ar * hi + ai * hr;
    hr = nhr;
    hi = nhi;
    const float outr = hr + ar * hpr - ai * hpi;
    const float outi = hi + ar * hpi + ai * hpr;
    hout16[base + d] = (bf16)outr;
    hout16[base + 256 + d] = (bf16)outi;
    if (t == 7) {
      o7r = outr;
      o7i = outi;
    }
  }
  hprev[p * 512 + d] = o7r;
  hprev[p * 512 + 256 + d] = o7i;
}

// probs = softmax(tok @ Wr) over 4 experts; one wave per token.
__global__ __launch_bounds__(64) void probs_k(const float* __restrict__ xn,
                                              const float* __restrict__ Wr,
                                              float* __restrict__ probs) {
  const int n = blockIdx.x;
  const int lane = threadIdx.x;
  float a0 = 0.f, a1 = 0.f, a2 = 0.f, a3 = 0.f;
  for (int c = lane; c < 512; c += 64) {
    const float x = xn[(size_t)n * 512 + c];
    a0 += x * Wr[c * 4 + 0];
    a1 += x * Wr[c * 4 + 1];
    a2 += x * Wr[c * 4 + 2];
    a3 += x * Wr[c * 4 + 3];
  }
#pragma unroll
  for (int off = 32; off > 0; off >>= 1) {
    a0 += __shfl_down(a0, off);
    a1 += __shfl_down(a1, off);
    a2 += __shfl_down(a2, off);
    a3 += __shfl_down(a3, off);
  }
  if (lane == 0) {
    float m = fmaxf(fmaxf(a0, a1), fmaxf(a2, a3));
    const float e0 = expf(a0 - m), e1 = expf(a1 - m), e2 = expf(a2 - m),
                e3 = expf(a3 - m);
    const float inv = 1.f / (e0 + e1 + e2 + e3);
    probs[n * 4 + 0] = e0 * inv;
    probs[n * 4 + 1] = e1 * inv;
    probs[n * 4 + 2] = e2 * inv;
    probs[n * 4 + 3] = e3 * inv;
  }
}

// z = a + b + c (fp32) + bf16 copy
__global__ __launch_bounds__(256) void add3_k(const float* __restrict__ a,
                                              const float* __restrict__ b,
                                              const float* __restrict__ c,
                                              float* __restrict__ o,
                                              bf16* __restrict__ o16) {
  const int i = blockIdx.x * 256 + threadIdx.x;
  const float v = a[i] + b[i] + c[i];
  o[i] = v;
  o16[i] = (bf16)v;
}

extern "C" void kernel_launch(void* const* d_in, const int* in_sizes, int n_in,
                              void* d_out, int out_size, void* d_ws,
                              size_t ws_size, hipStream_t stream) {
  const float* x_in = (const float*)d_in[0];
  const float* dt = (const float*)d_in[1];
  const float* Wenc = (const float*)d_in[2];
  const float* benc = (const float*)d_in[3];
  const float* Wdec = (const float*)d_in[4];
  const float* bdec = (const float*)d_in[5];
  const float* ln_sp_w = (const float*)d_in[6];
  const float* ln_sp_b = (const float*)d_in[7];
  const float* conv_w = (const float*)d_in[8];
  const float* conv_b = (const float*)d_in[9];
  const float* E_re = (const float*)d_in[10];
  const float* E_im = (const float*)d_in[11];
  const float* Ed_re = (const float*)d_in[12];
  const float* Ed_im = (const float*)d_in[13];
  const float* Ws_re = (const float*)d_in[14];
  const float* Ws_im = (const float*)d_in[15];
  const float* Wg = (const float*)d_in[16];
  const float* bg = (const float*)d_in[17];
  const float* lam_re = (const float*)d_in[18];
  const float* lam_im = (const float*)d_in[19];
  const float* ln_t_w = (const float*)d_in[20];
  const float* ln_t_b = (const float*)d_in[21];
  const float* Wr = (const float*)d_in[22];
  const float* W1 = (const float*)d_in[23];
  const float* W2 = (const float*)d_in[24];
  float* out = (float*)d_out;

  float* ws = (float*)d_ws;
  size_t off = 0;
  auto allocf = [&](size_t n) {
    float* p = ws + off;
    off += n;
    return p;
  };
  auto allocb = [&](size_t n) {
    bf16* p = (bf16*)(ws + off);
    off += n / 2;
    return p;
  };
  float* z = allocf((size_t)TOKS * 512);
  float* zn = allocf((size_t)TOKS * 512);
  float* xb = allocf((size_t)TOKS * 512);
  float* xe = allocf((size_t)TOKS * 512);
  float* yb = allocf((size_t)TOKS * 512);
  float* hprev = allocf(256 * 512);
  float* flux = allocf(512);
  float* xm = allocf(8 * 512);
  float* srcs = allocf(8 * 512);
  float* gts = allocf(8 * 256);
  float* opd = allocf(8 * 512);
  float* opf = allocf(8 * 512);
  float* probs = allocf((size_t)TOKS * 4);
  bf16* zn16 = allocb((size_t)TOKS * 512);
  bf16* xb16 = allocb((size_t)TOKS * 512);
  bf16* z16 = allocb((size_t)TOKS * 512);
  bf16* hb16 = allocb((size_t)TOKS * 512);
  bf16* hid16 = allocb((size_t)TOKS * 1024);
  bf16* Aenc16 = allocb((size_t)TOKS * 1024);
  bf16* WencT = allocb((size_t)512 * 1024);
  bf16* WdecT = allocb((size_t)1024 * 512);
  bf16* MEt = allocb((size_t)4 * 512 * 512);
  bf16* convBt = allocb((size_t)2 * 512 * 4608);
  bf16* W1T = allocb((size_t)8 * 1024 * 512);
  bf16* W2T = allocb((size_t)8 * 512 * 1024);

  hipMemsetAsync(hprev, 0, 256 * 512 * sizeof(float), stream);
  hipMemsetAsync(flux, 0, 512 * sizeof(float), stream);

  // ---- conversions (once per launch) ----
  cvt_enc_k<<<1024, 256, 0, stream>>>(x_in, Aenc16);
  cvtT_k<<<dim3(32, 16, 1), 256, 0, stream>>>(Wenc, WencT, 1024, 512);
  cvtT_k<<<dim3(16, 32, 1), 256, 0, stream>>>(Wdec, WdecT, 512, 1024);
  cvtT_k<<<dim3(16, 32, 8), 256, 0, stream>>>(W1, W1T, 512, 1024);
  cvtT_k<<<dim3(32, 16, 8), 256, 0, stream>>>(W2, W2T, 1024, 512);
  build_MEt_k<<<dim3(1024, 1, 4), 256, 0, stream>>>(E_re, E_im, Ed_re, Ed_im,
                                                    MEt);
  convBt16_k<<<dim3(9216, 1, 2), 256, 0, stream>>>(conv_w, convBt);

  // ---- encoder ----
  mgemm_k<EENC><<<dim3(32, 8), 256, 0, stream>>>(Aenc16, WencT, benc, nullptr,
                                                 nullptr, z, nullptr, 1024, 512);

  for (int l = 0; l < 2; l++) {
    ln_k<<<512, 256, 0, stream>>>(z, ln_sp_w + l * 512, ln_sp_b + l * 512, zn,
                                  zn16);
    mgemm_k<ECONV><<<dim3(32, 8), 256, 0, stream>>>(
        zn16, convBt + (size_t)l * 512 * 4608, conv_b + l * 512, z, nullptr, xb,
        xb16, 4608, 512);
    mgemm_k<ESQ><<<dim3(32, 8), 256, 0, stream>>>(
        xb16, MEt + (size_t)(l * 2) * 262144, nullptr, nullptr, nullptr, xe,
        nullptr, 512, 512);
    mean_k<<<dim3(8, 2), 256, 0, stream>>>(xe, xm);
    srcgate_k<<<dim3(8, 3), 256, 0, stream>>>(
        xm, Ws_re + l * 65536, Ws_im + l * 65536, Wg + l * 131072, bg + l * 256,
        srcs, gts);
    fluxrec_k<<<1, 256, 0, stream>>>(srcs, gts, lam_re + l * 256,
                                     lam_im + l * 256, dt, flux, opd, opf);
    time_scan_k<<<256, 256, 0, stream>>>(xe, gts, srcs, opd, opf, hb16, hprev);
    mgemm_k<ESQ><<<dim3(32, 8), 256, 0, stream>>>(
        hb16, MEt + (size_t)(l * 2 + 1) * 262144, nullptr, nullptr, nullptr, xe,
        nullptr, 512, 512);
    ln_k<<<512, 256, 0, stream>>>(xe, ln_t_w + l * 512, ln_t_b + l * 512, zn,
                                  zn16);
    probs_k<<<2048, 64, 0, stream>>>(zn, Wr + l * 2048, probs);
    hipMemsetAsync(yb, 0, (size_t)TOKS * 512 * sizeof(float), stream);
    for (int e = 0; e < 4; e++) {
      mgemm_k<EMOE1><<<dim3(32, 16), 256, 0, stream>>>(
          zn16, W1T + (size_t)(l * 4 + e) * 524288, nullptr, nullptr, nullptr,
          nullptr, hid16, 512, 1024);
      mgemm_k<EMOE2><<<dim3(32, 8), 256, 0, stream>>>(
          hid16, W2T + (size_t)(l * 4 + e) * 524288, nullptr, nullptr,
          probs + e, yb, nullptr, 1024, 512);
    }
    add3_k<<<4096, 256, 0, stream>>>(xb, zn, yb, z, z16);
  }

  // ---- decoder ----
  mgemm_k<EDEC><<<dim3(32, 16), 256, 0, stream>>>(z16, WdecT, bdec, nullptr,
                                                  nullptr, out, nullptr, 512,
                                                  1024);
}

// Round 5
// 498.419 us; speedup vs baseline: 4.2612x; 1.4497x over previous
//
#include <hip/hip_runtime.h>
#include <hip/hip_bf16.h>

// ---------------------------------------------------------------------------
// UniPhyModel: B=1 T=8 C=4 IH=IW=256 P=16 -> HP=WP=16, D=256 (2D=512), L=2,
// NE=4, FF=1024.  Token n = t*256 + hp*16 + wp (2048 tokens), channel
// c in [0,512): c<256 real, c>=256 imag.  bf16 MFMA GEMMs with register
// prefetch; split-K=4 for K>=4096 GEMMs; MoE experts fused (probs folded
// into gelu epilogue -> single K=4096 MoE2 GEMM).
// ---------------------------------------------------------------------------

#define TOKS 2048

typedef __bf16 bf16;
typedef __attribute__((ext_vector_type(8))) __bf16 bf16x8;
typedef __attribute__((ext_vector_type(4))) __bf16 bf16x4;
typedef __attribute__((ext_vector_type(4))) float f32x4;

enum GMode { EENC = 0, ECONV, ESQ, EMOE1, EMOE2, EDEC };

// MFMA GEMM: 64x64 tile/block, 4 waves each 32x32 (2x2 16x16x32 frags),
// BK=32, register-prefetch double buffering.
// SPLIT>1: blockIdx.z = K-slice, raw fp32 partials to Cpart.
// EMOE1: blockIdx.z = expert e; scale=probs[m*4+e]; out row stride 4096.
template <int MODE, int SPLIT>
__global__ __launch_bounds__(256) void mgemm_k(
    const bf16* __restrict__ A, const bf16* __restrict__ Bt,
    const float* __restrict__ bias, const float* __restrict__ addv,
    const float* __restrict__ scalev, float* __restrict__ C,
    bf16* __restrict__ C16, float* __restrict__ Cpart, int K, int N) {
  __shared__ __align__(16) bf16 As[64 * 40];
  __shared__ __align__(16) bf16 Bs[64 * 40];
  const int tid = threadIdx.x;
  const int bm = blockIdx.x * 64, bn = blockIdx.y * 64;
  const int lane = tid & 63, w = tid >> 6;
  const int wm = (w & 1) * 32, wn = (w >> 1) * 32;
  const int quad = lane >> 4, l16 = lane & 15;
  const int srow = tid >> 2, sko = (tid & 3) << 3;

  const int kbase = (SPLIT > 1) ? blockIdx.z * (K / SPLIT) : 0;
  const int kiter = K / (32 * SPLIT);
  if constexpr (MODE == EMOE1) Bt += (size_t)blockIdx.z * 524288;  // expert

  f32x4 acc[2][2] = {};

  int cv_t = 0, cv_h = 0, cv_w = 0;
  if constexpr (MODE == ECONV) {
    const int gm = bm + srow;
    cv_t = gm >> 8;
    cv_h = (gm >> 4) & 15;
    cv_w = gm & 15;
  }

  auto loadA = [&](int kt) -> bf16x8 {
    const int gk = kbase + kt * 32 + sko;
    if constexpr (MODE == ECONV) {
      const int s = gk >> 9, ci = gk & 511;
      const int kh = s / 3, kw = s - kh * 3;
      const int hh = cv_h + kh - 1, ww = cv_w + kw - 1;
      if (hh >= 0 && hh < 16 && ww >= 0 && ww < 16) {
        return *(const bf16x8*)&A[(size_t)(((cv_t << 8) + hh * 16 + ww) << 9) +
                                  ci];
      }
      bf16x8 zz;
#pragma unroll
      for (int q = 0; q < 8; q++) zz[q] = (bf16)0.0f;
      return zz;
    } else {
      return *(const bf16x8*)&A[(size_t)(bm + srow) * K + gk];
    }
  };
  auto loadB = [&](int kt) -> bf16x8 {
    return *(const bf16x8*)&Bt[(size_t)(bn + srow) * K + kbase + kt * 32 + sko];
  };

  bf16x8 pa = loadA(0), pb = loadB(0);
  for (int kt = 0; kt < kiter; kt++) {
    *(bf16x8*)&As[srow * 40 + sko] = pa;
    *(bf16x8*)&Bs[srow * 40 + sko] = pb;
    __syncthreads();
    if (kt + 1 < kiter) {  // prefetch next tile while computing this one
      pa = loadA(kt + 1);
      pb = loadB(kt + 1);
    }
    const bf16x8 a0 = *(const bf16x8*)&As[(wm + l16) * 40 + quad * 8];
    const bf16x8 a1 = *(const bf16x8*)&As[(wm + 16 + l16) * 40 + quad * 8];
    const bf16x8 b0 = *(const bf16x8*)&Bs[(wn + l16) * 40 + quad * 8];
    const bf16x8 b1 = *(const bf16x8*)&Bs[(wn + 16 + l16) * 40 + quad * 8];
    acc[0][0] = __builtin_amdgcn_mfma_f32_16x16x32_bf16(a0, b0, acc[0][0], 0, 0, 0);
    acc[0][1] = __builtin_amdgcn_mfma_f32_16x16x32_bf16(a0, b1, acc[0][1], 0, 0, 0);
    acc[1][0] = __builtin_amdgcn_mfma_f32_16x16x32_bf16(a1, b0, acc[1][0], 0, 0, 0);
    acc[1][1] = __builtin_amdgcn_mfma_f32_16x16x32_bf16(a1, b1, acc[1][1], 0, 0, 0);
    __syncthreads();
  }

  // epilogue; C/D layout: col = lane&15, row = quad*4 + reg
#pragma unroll
  for (int i = 0; i < 2; i++) {
#pragma unroll
    for (int j = 0; j < 2; j++) {
#pragma unroll
      for (int r = 0; r < 4; r++) {
        const int gm = bm + wm + i * 16 + quad * 4 + r;
        const int gn = bn + wn + j * 16 + l16;
        const float v = acc[i][j][r];
        if constexpr (SPLIT > 1) {
          Cpart[(size_t)blockIdx.z * ((size_t)gridDim.x * 64 * N) +
                (size_t)gm * N + gn] = v;
        } else if constexpr (MODE == EENC) {
          C[(size_t)gm * 512 + gn] = v + bias[gn];
        } else if constexpr (MODE == ESQ) {
          C[(size_t)gm * 512 + gn] = v;
        } else if constexpr (MODE == EMOE1) {
          const float t = 0.7978845608028654f * (v + 0.044715f * v * v * v);
          const float g = 0.5f * v * (1.f + tanhf(t));
          const float p = scalev[gm * 4 + blockIdx.z];
          C16[(size_t)gm * 4096 + blockIdx.z * 1024 + gn] = (bf16)(p * g);
        } else {  // EDEC
          const int t = gm >> 8, hp = (gm >> 4) & 15, wp = gm & 15;
          const int c = gn >> 8, ph = (gn >> 4) & 15, pw = gn & 15;
          C[(size_t)(((t * 4 + c) * 256 + hp * 16 + ph) << 8) + wp * 16 + pw] =
              v + bias[gn];
        }
      }
    }
  }
}

// conv combine: xb = sum(4 partials) + bias + residual z; fp32 + bf16 out.
__global__ __launch_bounds__(256) void conv_ep_k(
    const float* __restrict__ parts, const float* __restrict__ bias,
    const float* __restrict__ resid, float* __restrict__ xb,
    bf16* __restrict__ xb16) {
  const int i4 = (blockIdx.x * 256 + threadIdx.x) << 2;  // 1M floats
  const int c = i4 & 511;
  const float4 p0 = *(const float4*)&parts[i4];
  const float4 p1 = *(const float4*)&parts[1048576 + i4];
  const float4 p2 = *(const float4*)&parts[2097152 + i4];
  const float4 p3 = *(const float4*)&parts[3145728 + i4];
  const float4 bi = *(const float4*)&bias[c];
  const float4 rz = *(const float4*)&resid[i4];
  float4 o;
  o.x = p0.x + p1.x + p2.x + p3.x + bi.x + rz.x;
  o.y = p0.y + p1.y + p2.y + p3.y + bi.y + rz.y;
  o.z = p0.z + p1.z + p2.z + p3.z + bi.z + rz.z;
  o.w = p0.w + p1.w + p2.w + p3.w + bi.w + rz.w;
  *(float4*)&xb[i4] = o;
  bf16x4 o16 = {(bf16)o.x, (bf16)o.y, (bf16)o.z, (bf16)o.w};
  *(bf16x4*)&xb16[i4] = o16;
}

// final residual: z = xb + zn + sum(4 MoE2 partials); fp32 + bf16 out.
__global__ __launch_bounds__(256) void addf_k(const float* __restrict__ xb,
                                              const float* __restrict__ zn,
                                              const float* __restrict__ parts,
                                              float* __restrict__ z,
                                              bf16* __restrict__ z16) {
  const int i4 = (blockIdx.x * 256 + threadIdx.x) << 2;
  const float4 a = *(const float4*)&xb[i4];
  const float4 b = *(const float4*)&zn[i4];
  const float4 p0 = *(const float4*)&parts[i4];
  const float4 p1 = *(const float4*)&parts[1048576 + i4];
  const float4 p2 = *(const float4*)&parts[2097152 + i4];
  const float4 p3 = *(const float4*)&parts[3145728 + i4];
  float4 o;
  o.x = a.x + b.x + p0.x + p1.x + p2.x + p3.x;
  o.y = a.y + b.y + p0.y + p1.y + p2.y + p3.y;
  o.z = a.z + b.z + p0.z + p1.z + p2.z + p3.z;
  o.w = a.w + b.w + p0.w + p1.w + p2.w + p3.w;
  *(float4*)&z[i4] = o;
  bf16x4 o16 = {(bf16)o.x, (bf16)o.y, (bf16)o.z, (bf16)o.w};
  *(bf16x4*)&z16[i4] = o16;
}

// LayerNorm over 512 channels (one wave per token, 4 tokens/block).
// DO_PROBS: also compute probs = softmax(o @ Wr) per token.
template <bool DO_PROBS>
__global__ __launch_bounds__(256) void ln_k(
    const float* __restrict__ in, const float* __restrict__ w,
    const float* __restrict__ b, const float* __restrict__ Wr,
    float* __restrict__ out, bf16* __restrict__ out16,
    float* __restrict__ probs) {
  const int wv = threadIdx.x >> 6, lane = threadIdx.x & 63;
  const int n = (blockIdx.x << 2) + wv;
  const float* row = in + (size_t)n * 512;
  float v[8];
  float s = 0.f, s2 = 0.f;
#pragma unroll
  for (int i = 0; i < 8; i++) {
    const float x = row[(i << 6) + lane];
    v[i] = x;
    s += x;
    s2 += x * x;
  }
#pragma unroll
  for (int off = 32; off > 0; off >>= 1) {
    s += __shfl_down(s, off);
    s2 += __shfl_down(s2, off);
  }
  s = __shfl(s, 0);
  s2 = __shfl(s2, 0);
  const float m = s * (1.f / 512.f);
  const float var = s2 * (1.f / 512.f) - m * m;
  const float r = rsqrtf(var + 1e-5f);
  float a0 = 0.f, a1 = 0.f, a2 = 0.f, a3 = 0.f;
#pragma unroll
  for (int i = 0; i < 8; i++) {
    const int c = (i << 6) + lane;
    const float o = (v[i] - m) * r * w[c] + b[c];
    out[(size_t)n * 512 + c] = o;
    out16[(size_t)n * 512 + c] = (bf16)o;
    if constexpr (DO_PROBS) {
      a0 += o * Wr[c * 4 + 0];
      a1 += o * Wr[c * 4 + 1];
      a2 += o * Wr[c * 4 + 2];
      a3 += o * Wr[c * 4 + 3];
    }
  }
  if constexpr (DO_PROBS) {
#pragma unroll
    for (int off = 32; off > 0; off >>= 1) {
      a0 += __shfl_down(a0, off);
      a1 += __shfl_down(a1, off);
      a2 += __shfl_down(a2, off);
      a3 += __shfl_down(a3, off);
    }
    if (lane == 0) {
      const float mx = fmaxf(fmaxf(a0, a1), fmaxf(a2, a3));
      const float e0 = expf(a0 - mx), e1 = expf(a1 - mx), e2 = expf(a2 - mx),
                  e3 = expf(a3 - mx);
      const float inv = 1.f / (e0 + e1 + e2 + e3);
      probs[n * 4 + 0] = e0 * inv;
      probs[n * 4 + 1] = e1 * inv;
      probs[n * 4 + 2] = e2 * inv;
      probs[n * 4 + 3] = e3 * inv;
    }
  }
}

// x patches -> bf16 A_enc[n=2048][k=1024]
__global__ __launch_bounds__(256) void cvt_enc_k(const float* __restrict__ x,
                                                 bf16* __restrict__ Ae) {
  const int id = blockIdx.x * 256 + threadIdx.x;
  const int n = id >> 7;
  const int kc = (id & 127) << 3;
  const int t = n >> 8, hp = (n >> 4) & 15, wp = n & 15;
  const int c = kc >> 8, ph = (kc >> 4) & 15, pw = kc & 15;
  const float* src =
      &x[(size_t)(((t * 4 + c) * 256 + hp * 16 + ph) << 8) + wp * 16 + pw];
  const float4 v0 = *(const float4*)src;
  const float4 v1 = *(const float4*)(src + 4);
  bf16* d = &Ae[(size_t)n * 1024 + kc];
  d[0] = (bf16)v0.x; d[1] = (bf16)v0.y; d[2] = (bf16)v0.z; d[3] = (bf16)v0.w;
  d[4] = (bf16)v1.x; d[5] = (bf16)v1.y; d[6] = (bf16)v1.z; d[7] = (bf16)v1.w;
}

// fp32 [K][N] -> bf16 [N][K] tiled transpose; grid (K/32, N/32, batch)
__global__ __launch_bounds__(256) void cvtT_k(const float* __restrict__ src,
                                              bf16* __restrict__ dst, int K,
                                              int N) {
  __shared__ float tile[32][33];
  const size_t boff = (size_t)blockIdx.z * K * N;
  src += boff;
  dst += boff;
  const int k0 = blockIdx.x * 32, n0 = blockIdx.y * 32;
  const int tx = threadIdx.x & 31, ty = threadIdx.x >> 5;
#pragma unroll
  for (int r = 0; r < 4; r++)
    tile[ty + 8 * r][tx] = src[(size_t)(k0 + ty + 8 * r) * N + n0 + tx];
  __syncthreads();
#pragma unroll
  for (int r = 0; r < 4; r++)
    dst[(size_t)(n0 + ty + 8 * r) * K + k0 + tx] = (bf16)tile[tx][ty + 8 * r];
}

// W2 (l,e)[K=1024][N=512] -> bf16 W2Tc[l][n=512][kk=e*1024+k] (K_total=4096)
__global__ __launch_bounds__(256) void cvtW2_k(const float* __restrict__ W2,
                                               bf16* __restrict__ dst) {
  __shared__ float tile[32][33];
  const int z = blockIdx.z;  // l*4+e
  const int l = z >> 2, e = z & 3;
  const float* src = W2 + (size_t)z * 524288;
  bf16* d = dst + (size_t)l * 512 * 4096 + e * 1024;
  const int k0 = blockIdx.x * 32, n0 = blockIdx.y * 32;
  const int tx = threadIdx.x & 31, ty = threadIdx.x >> 5;
#pragma unroll
  for (int r = 0; r < 4; r++)
    tile[ty + 8 * r][tx] = src[(size_t)(k0 + ty + 8 * r) * 512 + n0 + tx];
  __syncthreads();
#pragma unroll
  for (int r = 0; r < 4; r++)
    d[(size_t)(n0 + ty + 8 * r) * 4096 + k0 + tx] = (bf16)tile[tx][ty + 8 * r];
}

// Build bf16 MEt[z][j=512][k=512] = M[k][j]
__global__ __launch_bounds__(256) void build_MEt_k(
    const float* __restrict__ E_re, const float* __restrict__ E_im,
    const float* __restrict__ Ed_re, const float* __restrict__ Ed_im,
    bf16* __restrict__ out) {
  const int z = blockIdx.z;
  const int l = z >> 1, which = z & 1;
  const float* Er = (which ? Ed_re : E_re) + l * 65536;
  const float* Ei = (which ? Ed_im : E_im) + l * 65536;
  bf16* dst = out + (size_t)z * 262144;
  const int idx = blockIdx.x * 256 + threadIdx.x;
  const int j = idx >> 9, k = idx & 511;
  const int kk = k & 255, jj = j & 255;
  const float er = Er[kk * 256 + jj], ei = Ei[kk * 256 + jj];
  const float v = (k < 256) ? ((j < 256) ? er : ei) : ((j < 256) ? -ei : er);
  dst[idx] = (bf16)v;
}

// conv_w (O,I,3,3) -> bf16 Bt[l][co][k=s*512+ci]
__global__ __launch_bounds__(256) void convBt16_k(const float* __restrict__ w,
                                                  bf16* __restrict__ dst) {
  const int l = blockIdx.z;
  const float* src = w + (size_t)l * 512 * 512 * 9;
  bf16* d = dst + (size_t)l * 512 * 4608;
  const int idx = blockIdx.x * 256 + threadIdx.x;
  const int co = idx / 4608;
  const int rem = idx - co * 4608;
  const int s = rem >> 9, ci = rem & 511;
  d[idx] = (bf16)src[(size_t)(co * 512 + ci) * 9 + s];
}

// Mean over 256 spatial positions
__global__ __launch_bounds__(256) void mean_k(const float* __restrict__ xe,
                                              float* __restrict__ xm) {
  const int t = blockIdx.x;
  const int c = blockIdx.y * 256 + threadIdx.x;
  float s = 0.f;
  for (int p = 0; p < 256; p++) s += xe[(size_t)((t << 8) + p) * 512 + c];
  xm[t * 512 + c] = s * (1.f / 256.f);
}

// Parallel src/gate over all t (no flux dependency).
__global__ __launch_bounds__(256) void srcgate_k(
    const float* __restrict__ xm, const float* __restrict__ Wsr,
    const float* __restrict__ Wsi, const float* __restrict__ Wg,
    const float* __restrict__ bg, float* __restrict__ srcs,
    float* __restrict__ gts) {
  const int t = blockIdx.x, part = blockIdx.y, d = threadIdx.x;
  __shared__ float sxm[512];
  for (int c = d; c < 512; c += 256) sxm[c] = xm[t * 512 + c];
  __syncthreads();
  if (part == 0) {
    float s0 = 0.f, s1 = 0.f, s2 = 0.f, s3 = 0.f;
#pragma unroll 4
    for (int e = 0; e < 256; e += 4) {
      s0 += sxm[e + 0] * Wsr[(e + 0) * 256 + d] - sxm[256 + e + 0] * Wsi[(e + 0) * 256 + d];
      s1 += sxm[e + 1] * Wsr[(e + 1) * 256 + d] - sxm[256 + e + 1] * Wsi[(e + 1) * 256 + d];
      s2 += sxm[e + 2] * Wsr[(e + 2) * 256 + d] - sxm[256 + e + 2] * Wsi[(e + 2) * 256 + d];
      s3 += sxm[e + 3] * Wsr[(e + 3) * 256 + d] - sxm[256 + e + 3] * Wsi[(e + 3) * 256 + d];
    }
    srcs[t * 512 + d] = (s0 + s1) + (s2 + s3);
  } else if (part == 1) {
    float s0 = 0.f, s1 = 0.f, s2 = 0.f, s3 = 0.f;
#pragma unroll 4
    for (int e = 0; e < 256; e += 4) {
      s0 += sxm[e + 0] * Wsi[(e + 0) * 256 + d] + sxm[256 + e + 0] * Wsr[(e + 0) * 256 + d];
      s1 += sxm[e + 1] * Wsi[(e + 1) * 256 + d] + sxm[256 + e + 1] * Wsr[(e + 1) * 256 + d];
      s2 += sxm[e + 2] * Wsi[(e + 2) * 256 + d] + sxm[256 + e + 2] * Wsr[(e + 2) * 256 + d];
      s3 += sxm[e + 3] * Wsi[(e + 3) * 256 + d] + sxm[256 + e + 3] * Wsr[(e + 3) * 256 + d];
    }
    srcs[t * 512 + 256 + d] = (s0 + s1) + (s2 + s3);
  } else {
    float s0 = 0.f, s1 = 0.f, s2 = 0.f, s3 = 0.f;
#pragma unroll 4
    for (int c = 0; c < 512; c += 4) {
      s0 += sxm[c + 0] * Wg[(c + 0) * 256 + d];
      s1 += sxm[c + 1] * Wg[(c + 1) * 256 + d];
      s2 += sxm[c + 2] * Wg[(c + 2) * 256 + d];
      s3 += sxm[c + 3] * Wg[(c + 3) * 256 + d];
    }
    const float ga = (s0 + s1) + (s2 + s3) + bg[d];
    gts[t * 256 + d] = 1.f / (1.f + expf(-ga));
  }
}

// Tiny sequential flux recurrence + opd/opf; one block.
__global__ __launch_bounds__(256) void fluxrec_k(
    const float* __restrict__ srcs, const float* __restrict__ gts,
    const float* __restrict__ lamre, const float* __restrict__ lamim,
    const float* __restrict__ dt, float* __restrict__ flux,
    float* __restrict__ opd, float* __restrict__ opf) {
  const int d = threadIdx.x;
  float fr = flux[d], fi = flux[256 + d];
  const float lr0 = lamre[d];
  const float sp = (lr0 > 20.f) ? lr0 : log1pf(expf(lr0));
  const float lre = -(sp + 0.01f);
  const float lim = lamim[d];
  const float den = lre * lre + lim * lim;
#pragma unroll
  for (int t = 0; t < 8; t++) {
    const float g = gts[t * 256 + d];
    const float sr = srcs[t * 512 + d], si = srcs[t * 512 + 256 + d];
    fr = g * fr + (1.f - g) * sr;
    fi = g * fi + (1.f - g) * si;
    const float dtv = dt[t];
    const float er = expf(lre * dtv);
    const float odr = er * cosf(lim * dtv);
    const float odi = er * sinf(lim * dtv);
    opd[t * 512 + d] = odr;
    opd[t * 512 + 256 + d] = odi;
    const float nr = odr - 1.f, ni = odi;
    opf[t * 512 + d] = (nr * lre + ni * lim) / den;
    opf[t * 512 + 256 + d] = (ni * lre - nr * lim) / den;
  }
  flux[d] = fr;
  flux[256 + d] = fi;
}

// Per-(p,d) time scan -> bf16 h, updates fp32 hprev
__global__ __launch_bounds__(256) void time_scan_k(
    const float* __restrict__ xe, const float* __restrict__ gts,
    const float* __restrict__ srcs, const float* __restrict__ opd,
    const float* __restrict__ opf, bf16* __restrict__ hout16,
    float* __restrict__ hprev) {
  const int d = threadIdx.x;
  const int p = blockIdx.x;
  float hr = 0.f, hi = 0.f;
  const float hpr = hprev[p * 512 + d], hpi = hprev[p * 512 + 256 + d];
  float o7r = 0.f, o7i = 0.f;
  for (int t = 0; t < 8; t++) {
    const size_t base = (size_t)((t << 8) + p) * 512;
    const float xr = xe[base + d], xi = xe[base + 256 + d];
    const float g = gts[t * 256 + d];
    const float sr = srcs[t * 512 + d], si = srcs[t * 512 + 256 + d];
    const float fr = xr * g + sr * (1.f - g);
    const float fi = xi * g + si * (1.f - g);
    const float ofr = opf[t * 512 + d], ofi = opf[t * 512 + 256 + d];
    const float ur = fr * ofr - fi * ofi;
    const float ui = fr * ofi + fi * ofr;
    const float ar = opd[t * 512 + d], ai = opd[t * 512 + 256 + d];
    const float nhr = ur + ar * hr - ai * hi;
    const float nhi = ui + ar * hi + ai * hr;
    hr = nhr;
    hi = nhi;
    const float outr = hr + ar * hpr - ai * hpi;
    const float outi = hi + ar * hpi + ai * hpr;
    hout16[base + d] = (bf16)outr;
    hout16[base + 256 + d] = (bf16)outi;
    if (t == 7) {
      o7r = outr;
      o7i = outi;
    }
  }
  hprev[p * 512 + d] = o7r;
  hprev[p * 512 + 256 + d] = o7i;
}

extern "C" void kernel_launch(void* const* d_in, const int* in_sizes, int n_in,
                              void* d_out, int out_size, void* d_ws,
                              size_t ws_size, hipStream_t stream) {
  const float* x_in = (const float*)d_in[0];
  const float* dt = (const float*)d_in[1];
  const float* Wenc = (const float*)d_in[2];
  const float* benc = (const float*)d_in[3];
  const float* Wdec = (const float*)d_in[4];
  const float* bdec = (const float*)d_in[5];
  const float* ln_sp_w = (const float*)d_in[6];
  const float* ln_sp_b = (const float*)d_in[7];
  const float* conv_w = (const float*)d_in[8];
  const float* conv_b = (const float*)d_in[9];
  const float* E_re = (const float*)d_in[10];
  const float* E_im = (const float*)d_in[11];
  const float* Ed_re = (const float*)d_in[12];
  const float* Ed_im = (const float*)d_in[13];
  const float* Ws_re = (const float*)d_in[14];
  const float* Ws_im = (const float*)d_in[15];
  const float* Wg = (const float*)d_in[16];
  const float* bg = (const float*)d_in[17];
  const float* lam_re = (const float*)d_in[18];
  const float* lam_im = (const float*)d_in[19];
  const float* ln_t_w = (const float*)d_in[20];
  const float* ln_t_b = (const float*)d_in[21];
  const float* Wr = (const float*)d_in[22];
  const float* W1 = (const float*)d_in[23];
  const float* W2 = (const float*)d_in[24];
  float* out = (float*)d_out;

  float* ws = (float*)d_ws;
  size_t off = 0;
  auto allocf = [&](size_t n) {
    float* p = ws + off;
    off += n;
    return p;
  };
  auto allocb = [&](size_t n) {
    bf16* p = (bf16*)(ws + off);
    off += n / 2;
    return p;
  };
  float* z = allocf((size_t)TOKS * 512);
  float* zn = allocf((size_t)TOKS * 512);
  float* xb = allocf((size_t)TOKS * 512);
  float* xe = allocf((size_t)TOKS * 512);
  float* parts = allocf((size_t)4 * TOKS * 512);  // split-K partials (16 MB)
  float* hprev = allocf(256 * 512);
  float* flux = allocf(512);
  float* xm = allocf(8 * 512);
  float* srcs = allocf(8 * 512);
  float* gts = allocf(8 * 256);
  float* opd = allocf(8 * 512);
  float* opf = allocf(8 * 512);
  float* probs = allocf((size_t)TOKS * 4);
  bf16* zn16 = allocb((size_t)TOKS * 512);
  bf16* xb16 = allocb((size_t)TOKS * 512);
  bf16* z16 = allocb((size_t)TOKS * 512);
  bf16* hb16 = allocb((size_t)TOKS * 512);
  bf16* hid16 = allocb((size_t)TOKS * 4096);  // [n][e*1024+f], probs folded
  bf16* Aenc16 = allocb((size_t)TOKS * 1024);
  bf16* WencT = allocb((size_t)512 * 1024);
  bf16* WdecT = allocb((size_t)1024 * 512);
  bf16* MEt = allocb((size_t)4 * 512 * 512);
  bf16* convBt = allocb((size_t)2 * 512 * 4608);
  bf16* W1T = allocb((size_t)8 * 1024 * 512);
  bf16* W2Tc = allocb((size_t)2 * 512 * 4096);  // concat experts along K

  hipMemsetAsync(hprev, 0, 256 * 512 * sizeof(float), stream);
  hipMemsetAsync(flux, 0, 512 * sizeof(float), stream);

  // ---- conversions (once per launch) ----
  cvt_enc_k<<<1024, 256, 0, stream>>>(x_in, Aenc16);
  cvtT_k<<<dim3(32, 16, 1), 256, 0, stream>>>(Wenc, WencT, 1024, 512);
  cvtT_k<<<dim3(16, 32, 1), 256, 0, stream>>>(Wdec, WdecT, 512, 1024);
  cvtT_k<<<dim3(16, 32, 8), 256, 0, stream>>>(W1, W1T, 512, 1024);
  cvtW2_k<<<dim3(32, 16, 8), 256, 0, stream>>>(W2, W2Tc);
  build_MEt_k<<<dim3(1024, 1, 4), 256, 0, stream>>>(E_re, E_im, Ed_re, Ed_im,
                                                    MEt);
  convBt16_k<<<dim3(9216, 1, 2), 256, 0, stream>>>(conv_w, convBt);

  // ---- encoder ----
  mgemm_k<EENC, 1><<<dim3(32, 8), 256, 0, stream>>>(
      Aenc16, WencT, benc, nullptr, nullptr, z, nullptr, nullptr, 1024, 512);

  for (int l = 0; l < 2; l++) {
    ln_k<false><<<512, 256, 0, stream>>>(z, ln_sp_w + l * 512,
                                         ln_sp_b + l * 512, nullptr, zn, zn16,
                                         nullptr);
    mgemm_k<ECONV, 4><<<dim3(32, 8, 4), 256, 0, stream>>>(
        zn16, convBt + (size_t)l * 512 * 4608, nullptr, nullptr, nullptr,
        nullptr, nullptr, parts, 4608, 512);
    conv_ep_k<<<1024, 256, 0, stream>>>(parts, conv_b + l * 512, z, xb, xb16);
    mgemm_k<ESQ, 1><<<dim3(32, 8), 256, 0, stream>>>(
        xb16, MEt + (size_t)(l * 2) * 262144, nullptr, nullptr, nullptr, xe,
        nullptr, nullptr, 512, 512);
    mean_k<<<dim3(8, 2), 256, 0, stream>>>(xe, xm);
    srcgate_k<<<dim3(8, 3), 256, 0, stream>>>(
        xm, Ws_re + l * 65536, Ws_im + l * 65536, Wg + l * 131072, bg + l * 256,
        srcs, gts);
    fluxrec_k<<<1, 256, 0, stream>>>(srcs, gts, lam_re + l * 256,
                                     lam_im + l * 256, dt, flux, opd, opf);
    time_scan_k<<<256, 256, 0, stream>>>(xe, gts, srcs, opd, opf, hb16, hprev);
    mgemm_k<ESQ, 1><<<dim3(32, 8), 256, 0, stream>>>(
        hb16, MEt + (size_t)(l * 2 + 1) * 262144, nullptr, nullptr, nullptr, xe,
        nullptr, nullptr, 512, 512);
    ln_k<true><<<512, 256, 0, stream>>>(xe, ln_t_w + l * 512, ln_t_b + l * 512,
                                        Wr + l * 2048, zn, zn16, probs);
    // MoE1: all 4 experts, probs folded into gelu output
    mgemm_k<EMOE1, 1><<<dim3(32, 16, 4), 256, 0, stream>>>(
        zn16, W1T + (size_t)l * 4 * 524288, nullptr, nullptr, probs, nullptr,
        hid16, nullptr, 512, 1024);
    // MoE2: single GEMM over concatenated expert hiddens, split-K=4
    mgemm_k<EMOE2, 4><<<dim3(32, 8, 4), 256, 0, stream>>>(
        hid16, W2Tc + (size_t)l * 512 * 4096, nullptr, nullptr, nullptr,
        nullptr, nullptr, parts, 4096, 512);
    addf_k<<<1024, 256, 0, stream>>>(xb, zn, parts, z, z16);
  }

  // ---- decoder ----
  mgemm_k<EDEC, 1><<<dim3(32, 16), 256, 0, stream>>>(
      z16, WdecT, bdec, nullptr, nullptr, out, nullptr, nullptr, 512, 1024);
}

// Round 6
// 495.123 us; speedup vs baseline: 4.2895x; 1.0067x over previous
//
#include <hip/hip_runtime.h>
#include <hip/hip_bf16.h>

// ---------------------------------------------------------------------------
// UniPhyModel: B=1 T=8 C=4 IH=IW=256 P=16 -> HP=WP=16, D=256 (2D=512), L=2,
// NE=4, FF=1024.  Token n = t*256 + hp*16 + wp (2048 tokens), channel
// c in [0,512): c<256 real, c>=256 imag.
// bf16 MFMA GEMMs. 64x64-tile kernel for square-ish shapes; 128x128-tile
// (wave 64x64 = 4x4 frags) for fat-K GEMMs (conv/MoE), split-K=4.
// flux recurrence deleted (provably dead w.r.t. model output).
// All weight conversions merged into one kernel launch.
// ---------------------------------------------------------------------------

#define TOKS 2048

typedef __bf16 bf16;
typedef __attribute__((ext_vector_type(8))) __bf16 bf16x8;
typedef __attribute__((ext_vector_type(4))) __bf16 bf16x4;
typedef __attribute__((ext_vector_type(4))) float f32x4;

enum GMode { EENC = 0, ECONV, ESQ, EMOE1, EMOE2, EDEC };

// ---------- 64x64 tile GEMM (4 waves, each 32x32 = 2x2 frags) ----------
template <int MODE>
__global__ __launch_bounds__(256) void mgemm_k(
    const bf16* __restrict__ A, const bf16* __restrict__ Bt,
    const float* __restrict__ bias, float* __restrict__ C, int K, int N) {
  __shared__ __align__(16) bf16 As[64 * 40];
  __shared__ __align__(16) bf16 Bs[64 * 40];
  const int tid = threadIdx.x;
  const int bm = blockIdx.x * 64, bn = blockIdx.y * 64;
  const int lane = tid & 63, w = tid >> 6;
  const int wm = (w & 1) * 32, wn = (w >> 1) * 32;
  const int quad = lane >> 4, l16 = lane & 15;
  const int srow = tid >> 2, sko = (tid & 3) << 3;

  f32x4 acc[2][2] = {};
  const int kiter = K / 32;

  auto loadA = [&](int kt) -> bf16x8 {
    return *(const bf16x8*)&A[(size_t)(bm + srow) * K + kt * 32 + sko];
  };
  auto loadB = [&](int kt) -> bf16x8 {
    return *(const bf16x8*)&Bt[(size_t)(bn + srow) * K + kt * 32 + sko];
  };

  bf16x8 pa = loadA(0), pb = loadB(0);
  for (int kt = 0; kt < kiter; kt++) {
    *(bf16x8*)&As[srow * 40 + sko] = pa;
    *(bf16x8*)&Bs[srow * 40 + sko] = pb;
    __syncthreads();
    if (kt + 1 < kiter) {
      pa = loadA(kt + 1);
      pb = loadB(kt + 1);
    }
    const bf16x8 a0 = *(const bf16x8*)&As[(wm + l16) * 40 + quad * 8];
    const bf16x8 a1 = *(const bf16x8*)&As[(wm + 16 + l16) * 40 + quad * 8];
    const bf16x8 b0 = *(const bf16x8*)&Bs[(wn + l16) * 40 + quad * 8];
    const bf16x8 b1 = *(const bf16x8*)&Bs[(wn + 16 + l16) * 40 + quad * 8];
    acc[0][0] = __builtin_amdgcn_mfma_f32_16x16x32_bf16(a0, b0, acc[0][0], 0, 0, 0);
    acc[0][1] = __builtin_amdgcn_mfma_f32_16x16x32_bf16(a0, b1, acc[0][1], 0, 0, 0);
    acc[1][0] = __builtin_amdgcn_mfma_f32_16x16x32_bf16(a1, b0, acc[1][0], 0, 0, 0);
    acc[1][1] = __builtin_amdgcn_mfma_f32_16x16x32_bf16(a1, b1, acc[1][1], 0, 0, 0);
    __syncthreads();
  }

#pragma unroll
  for (int i = 0; i < 2; i++) {
#pragma unroll
    for (int j = 0; j < 2; j++) {
#pragma unroll
      for (int r = 0; r < 4; r++) {
        const int gm = bm + wm + i * 16 + quad * 4 + r;
        const int gn = bn + wn + j * 16 + l16;
        const float v = acc[i][j][r];
        if constexpr (MODE == EENC) {
          C[(size_t)gm * 512 + gn] = v + bias[gn];
        } else if constexpr (MODE == ESQ) {
          C[(size_t)gm * 512 + gn] = v;
        } else {  // EDEC scatter to (B,T,C,IH,IW)
          const int t = gm >> 8, hp = (gm >> 4) & 15, wp = gm & 15;
          const int c = gn >> 8, ph = (gn >> 4) & 15, pw = gn & 15;
          C[(size_t)(((t * 4 + c) * 256 + hp * 16 + ph) << 8) + wp * 16 + pw] =
              v + bias[gn];
        }
      }
    }
  }
}

// ---------- 128x128 tile GEMM (4 waves, each 64x64 = 4x4 frags) ----------
// ECONV: im2col halo gather, SPLIT=4 -> fp32 partials (N=512).
// EMOE2: SPLIT=4 -> fp32 partials (N=512).
// EMOE1: z = expert; gelu*probs epilogue -> C16 row stride 4096.
template <int MODE, int SPLIT>
__global__ __launch_bounds__(256) void mgemm2_k(
    const bf16* __restrict__ A, const bf16* __restrict__ Bt,
    const float* __restrict__ scalev, bf16* __restrict__ C16,
    float* __restrict__ Cpart, int K, int N) {
  __shared__ __align__(16) bf16 As[128 * 40];
  __shared__ __align__(16) bf16 Bs[128 * 40];
  const int tid = threadIdx.x;
  const int bm = blockIdx.x * 128, bn = blockIdx.y * 128;
  const int lane = tid & 63, w = tid >> 6;
  const int wm = (w & 1) * 64, wn = (w >> 1) * 64;
  const int quad = lane >> 4, l16 = lane & 15;
  const int srow = tid >> 1, sko = (tid & 1) << 4;  // 16 bf16 per thread

  const int kbase = (SPLIT > 1) ? blockIdx.z * (K / SPLIT) : 0;
  const int kiter = K / (32 * SPLIT);
  if constexpr (MODE == EMOE1) Bt += (size_t)blockIdx.z * 524288;

  f32x4 acc[4][4] = {};

  int cv_t = 0, cv_h = 0, cv_w = 0;
  if constexpr (MODE == ECONV) {
    const int gm = bm + srow;
    cv_t = gm >> 8;
    cv_h = (gm >> 4) & 15;
    cv_w = gm & 15;
  }

  auto loadA = [&](int kt, int half) -> bf16x8 {
    const int gk = kbase + kt * 32 + sko + half * 8;
    if constexpr (MODE == ECONV) {
      const int s = gk >> 9, ci = gk & 511;  // 8-chunk never crosses s
      const int kh = s / 3, kw = s - kh * 3;
      const int hh = cv_h + kh - 1, ww = cv_w + kw - 1;
      if (hh >= 0 && hh < 16 && ww >= 0 && ww < 16)
        return *(const bf16x8*)&A[(size_t)(((cv_t << 8) + hh * 16 + ww) << 9) +
                                  ci];
      bf16x8 zz;
#pragma unroll
      for (int q = 0; q < 8; q++) zz[q] = (bf16)0.0f;
      return zz;
    } else {
      return *(const bf16x8*)&A[(size_t)(bm + srow) * K + gk];
    }
  };
  auto loadB = [&](int kt, int half) -> bf16x8 {
    return *(const bf16x8*)&Bt[(size_t)(bn + srow) * K + kbase + kt * 32 + sko +
                               half * 8];
  };

  bf16x8 pa0 = loadA(0, 0), pa1 = loadA(0, 1);
  bf16x8 pb0 = loadB(0, 0), pb1 = loadB(0, 1);
  for (int kt = 0; kt < kiter; kt++) {
    *(bf16x8*)&As[srow * 40 + sko] = pa0;
    *(bf16x8*)&As[srow * 40 + sko + 8] = pa1;
    *(bf16x8*)&Bs[srow * 40 + sko] = pb0;
    *(bf16x8*)&Bs[srow * 40 + sko + 8] = pb1;
    __syncthreads();
    if (kt + 1 < kiter) {
      pa0 = loadA(kt + 1, 0);
      pa1 = loadA(kt + 1, 1);
      pb0 = loadB(kt + 1, 0);
      pb1 = loadB(kt + 1, 1);
    }
    bf16x8 af[4], bfr[4];
#pragma unroll
    for (int i = 0; i < 4; i++)
      af[i] = *(const bf16x8*)&As[(wm + i * 16 + l16) * 40 + quad * 8];
#pragma unroll
    for (int j = 0; j < 4; j++)
      bfr[j] = *(const bf16x8*)&Bs[(wn + j * 16 + l16) * 40 + quad * 8];
#pragma unroll
    for (int i = 0; i < 4; i++)
#pragma unroll
      for (int j = 0; j < 4; j++)
        acc[i][j] =
            __builtin_amdgcn_mfma_f32_16x16x32_bf16(af[i], bfr[j], acc[i][j], 0, 0, 0);
    __syncthreads();
  }

#pragma unroll
  for (int i = 0; i < 4; i++) {
#pragma unroll
    for (int j = 0; j < 4; j++) {
#pragma unroll
      for (int r = 0; r < 4; r++) {
        const int gm = bm + wm + i * 16 + quad * 4 + r;
        const int gn = bn + wn + j * 16 + l16;
        const float v = acc[i][j][r];
        if constexpr (SPLIT > 1) {
          Cpart[(size_t)blockIdx.z * 1048576 + (size_t)gm * 512 + gn] = v;
        } else {  // EMOE1
          const float t = 0.7978845608028654f * (v + 0.044715f * v * v * v);
          const float g = 0.5f * v * (1.f + tanhf(t));
          const float p = scalev[gm * 4 + blockIdx.z];
          C16[(size_t)gm * 4096 + blockIdx.z * 1024 + gn] = (bf16)(p * g);
        }
      }
    }
  }
}

// conv combine: xb = sum(4 partials) + bias + residual z; fp32 + bf16 out.
__global__ __launch_bounds__(256) void conv_ep_k(
    const float* __restrict__ parts, const float* __restrict__ bias,
    const float* __restrict__ resid, float* __restrict__ xb,
    bf16* __restrict__ xb16) {
  const int i4 = (blockIdx.x * 256 + threadIdx.x) << 2;
  const int c = i4 & 511;
  const float4 p0 = *(const float4*)&parts[i4];
  const float4 p1 = *(const float4*)&parts[1048576 + i4];
  const float4 p2 = *(const float4*)&parts[2097152 + i4];
  const float4 p3 = *(const float4*)&parts[3145728 + i4];
  const float4 bi = *(const float4*)&bias[c];
  const float4 rz = *(const float4*)&resid[i4];
  float4 o;
  o.x = p0.x + p1.x + p2.x + p3.x + bi.x + rz.x;
  o.y = p0.y + p1.y + p2.y + p3.y + bi.y + rz.y;
  o.z = p0.z + p1.z + p2.z + p3.z + bi.z + rz.z;
  o.w = p0.w + p1.w + p2.w + p3.w + bi.w + rz.w;
  *(float4*)&xb[i4] = o;
  bf16x4 o16 = {(bf16)o.x, (bf16)o.y, (bf16)o.z, (bf16)o.w};
  *(bf16x4*)&xb16[i4] = o16;
}

// final residual: z = xb + zn + sum(4 MoE2 partials); fp32 + bf16 out.
__global__ __launch_bounds__(256) void addf_k(const float* __restrict__ xb,
                                              const float* __restrict__ zn,
                                              const float* __restrict__ parts,
                                              float* __restrict__ z,
                                              bf16* __restrict__ z16) {
  const int i4 = (blockIdx.x * 256 + threadIdx.x) << 2;
  const float4 a = *(const float4*)&xb[i4];
  const float4 b = *(const float4*)&zn[i4];
  const float4 p0 = *(const float4*)&parts[i4];
  const float4 p1 = *(const float4*)&parts[1048576 + i4];
  const float4 p2 = *(const float4*)&parts[2097152 + i4];
  const float4 p3 = *(const float4*)&parts[3145728 + i4];
  float4 o;
  o.x = a.x + b.x + p0.x + p1.x + p2.x + p3.x;
  o.y = a.y + b.y + p0.y + p1.y + p2.y + p3.y;
  o.z = a.z + b.z + p0.z + p1.z + p2.z + p3.z;
  o.w = a.w + b.w + p0.w + p1.w + p2.w + p3.w;
  *(float4*)&z[i4] = o;
  bf16x4 o16 = {(bf16)o.x, (bf16)o.y, (bf16)o.z, (bf16)o.w};
  *(bf16x4*)&z16[i4] = o16;
}

// LayerNorm over 512 channels (one wave/token, 4 tokens/block); optional probs.
template <bool DO_PROBS>
__global__ __launch_bounds__(256) void ln_k(
    const float* __restrict__ in, const float* __restrict__ w,
    const float* __restrict__ b, const float* __restrict__ Wr,
    float* __restrict__ out, bf16* __restrict__ out16,
    float* __restrict__ probs) {
  const int wv = threadIdx.x >> 6, lane = threadIdx.x & 63;
  const int n = (blockIdx.x << 2) + wv;
  const float* row = in + (size_t)n * 512;
  float v[8];
  float s = 0.f, s2 = 0.f;
#pragma unroll
  for (int i = 0; i < 8; i++) {
    const float x = row[(i << 6) + lane];
    v[i] = x;
    s += x;
    s2 += x * x;
  }
#pragma unroll
  for (int off = 32; off > 0; off >>= 1) {
    s += __shfl_down(s, off);
    s2 += __shfl_down(s2, off);
  }
  s = __shfl(s, 0);
  s2 = __shfl(s2, 0);
  const float m = s * (1.f / 512.f);
  const float var = s2 * (1.f / 512.f) - m * m;
  const float r = rsqrtf(var + 1e-5f);
  float a0 = 0.f, a1 = 0.f, a2 = 0.f, a3 = 0.f;
#pragma unroll
  for (int i = 0; i < 8; i++) {
    const int c = (i << 6) + lane;
    const float o = (v[i] - m) * r * w[c] + b[c];
    out[(size_t)n * 512 + c] = o;
    out16[(size_t)n * 512 + c] = (bf16)o;
    if constexpr (DO_PROBS) {
      a0 += o * Wr[c * 4 + 0];
      a1 += o * Wr[c * 4 + 1];
      a2 += o * Wr[c * 4 + 2];
      a3 += o * Wr[c * 4 + 3];
    }
  }
  if constexpr (DO_PROBS) {
#pragma unroll
    for (int off = 32; off > 0; off >>= 1) {
      a0 += __shfl_down(a0, off);
      a1 += __shfl_down(a1, off);
      a2 += __shfl_down(a2, off);
      a3 += __shfl_down(a3, off);
    }
    if (lane == 0) {
      const float mx = fmaxf(fmaxf(a0, a1), fmaxf(a2, a3));
      const float e0 = expf(a0 - mx), e1 = expf(a1 - mx), e2 = expf(a2 - mx),
                  e3 = expf(a3 - mx);
      const float inv = 1.f / (e0 + e1 + e2 + e3);
      probs[n * 4 + 0] = e0 * inv;
      probs[n * 4 + 1] = e1 * inv;
      probs[n * 4 + 2] = e2 * inv;
      probs[n * 4 + 3] = e3 * inv;
    }
  }
}

// ---------- merged conversions: one launch, block-range decode ----------
// [0,1024): enc patches -> Aenc16
// [1024,1536): Wenc^T    [1536,2048): Wdec^T
// [2048,6144): W1^T (8)  [6144,10240): W2 -> W2Tc (8, concat experts)
// [10240,14336): MEt (4) [14336,18944): convBt (2)
__global__ __launch_bounds__(256) void cvt_all_k(
    const float* __restrict__ x, const float* __restrict__ Wenc,
    const float* __restrict__ Wdec, const float* __restrict__ W1,
    const float* __restrict__ W2, const float* __restrict__ E_re,
    const float* __restrict__ E_im, const float* __restrict__ Ed_re,
    const float* __restrict__ Ed_im, const float* __restrict__ conv_w,
    bf16* __restrict__ Ae, bf16* __restrict__ WencT, bf16* __restrict__ WdecT,
    bf16* __restrict__ W1T, bf16* __restrict__ W2Tc, bf16* __restrict__ MEt,
    bf16* __restrict__ convBt) {
  __shared__ float tile[32][33];
  const int tid = threadIdx.x;
  int b = blockIdx.x;
  const int tx = tid & 31, ty = tid >> 5;
  auto tpose = [&](const float* src, bf16* dst, int K, int N, int dstride,
                   int k0, int n0) {
#pragma unroll
    for (int r = 0; r < 4; r++)
      tile[ty + 8 * r][tx] = src[(size_t)(k0 + ty + 8 * r) * N + n0 + tx];
    __syncthreads();
#pragma unroll
    for (int r = 0; r < 4; r++)
      dst[(size_t)(n0 + ty + 8 * r) * dstride + k0 + tx] =
          (bf16)tile[tx][ty + 8 * r];
  };
  if (b < 1024) {  // encoder patch gather + cast
    const int id = b * 256 + tid;
    const int n = id >> 7;
    const int kc = (id & 127) << 3;
    const int t = n >> 8, hp = (n >> 4) & 15, wp = n & 15;
    const int c = kc >> 8, ph = (kc >> 4) & 15, pw = kc & 15;
    const float* src =
        &x[(size_t)(((t * 4 + c) * 256 + hp * 16 + ph) << 8) + wp * 16 + pw];
    const float4 v0 = *(const float4*)src;
    const float4 v1 = *(const float4*)(src + 4);
    bf16* d = &Ae[(size_t)n * 1024 + kc];
    d[0] = (bf16)v0.x; d[1] = (bf16)v0.y; d[2] = (bf16)v0.z; d[3] = (bf16)v0.w;
    d[4] = (bf16)v1.x; d[5] = (bf16)v1.y; d[6] = (bf16)v1.z; d[7] = (bf16)v1.w;
    return;
  }
  b -= 1024;
  if (b < 512) {  // Wenc [1024][512] -> [512][1024]
    tpose(Wenc, WencT, 1024, 512, 1024, (b & 31) * 32, (b >> 5) * 32);
    return;
  }
  b -= 512;
  if (b < 512) {  // Wdec [512][1024] -> [1024][512]
    tpose(Wdec, WdecT, 512, 1024, 512, (b & 15) * 32, (b >> 4) * 32);
    return;
  }
  b -= 512;
  if (b < 4096) {  // W1 (8)[512][1024] -> [1024][512]
    const int z = b >> 9, rem = b & 511;
    tpose(W1 + (size_t)z * 524288, W1T + (size_t)z * 524288, 512, 1024, 512,
          (rem & 15) * 32, (rem >> 4) * 32);
    return;
  }
  b -= 4096;
  if (b < 4096) {  // W2 (l,e)[1024][512] -> W2Tc[l][512][e*1024+k] stride 4096
    const int z = b >> 9, rem = b & 511;
    const int l = z >> 2, e = z & 3;
    tpose(W2 + (size_t)z * 524288, W2Tc + (size_t)l * 2097152 + e * 1024, 1024,
          512, 4096, (rem & 31) * 32, (rem >> 5) * 32);
    return;
  }
  b -= 4096;
  if (b < 4096) {  // MEt[z][j=512][k=512] = [[Er,Ei],[-Ei,Er]]^T
    const int z = b >> 10;
    const int l = z >> 1, which = z & 1;
    const float* Er = (which ? Ed_re : E_re) + l * 65536;
    const float* Ei = (which ? Ed_im : E_im) + l * 65536;
    bf16* dst = MEt + (size_t)z * 262144;
    const int idx = (b & 1023) * 256 + tid;
    const int j = idx >> 9, k = idx & 511;
    const int kk = k & 255, jj = j & 255;
    const float er = Er[kk * 256 + jj], ei = Ei[kk * 256 + jj];
    const float v = (k < 256) ? ((j < 256) ? er : ei) : ((j < 256) ? -ei : er);
    dst[idx] = (bf16)v;
    return;
  }
  b -= 4096;
  {  // conv_w (l,O,I,3,3) -> convBt[l][co][s*512+ci], 4 elems/thread
    const int z = b / 2304;
    const int rem = b - z * 2304;
    const float* src = conv_w + (size_t)z * 2359296;
    bf16* d = convBt + (size_t)z * 2359296;
    const int idx = (rem * 256 + tid) << 2;
    const int co = idx / 4608;
    const int r2 = idx - co * 4608;
    const int s = r2 >> 9, ci = r2 & 511;
    bf16x4 o;
#pragma unroll
    for (int q = 0; q < 4; q++)
      o[q] = (bf16)src[(size_t)(co * 512 + ci + q) * 9 + s];
    *(bf16x4*)&d[idx] = o;
  }
}

// Parallel src/gate with fused spatial mean. grid (8 t, 3 part) x 256.
__global__ __launch_bounds__(256) void srcgate_k(
    const float* __restrict__ xe, const float* __restrict__ Wsr,
    const float* __restrict__ Wsi, const float* __restrict__ Wg,
    const float* __restrict__ bg, float* __restrict__ srcs,
    float* __restrict__ gts) {
  const int t = blockIdx.x, part = blockIdx.y, d = threadIdx.x;
  __shared__ float sxm[512];
  for (int c = d; c < 512; c += 256) {
    const float* col = xe + (size_t)(t << 8) * 512 + c;
    float s0 = 0.f, s1 = 0.f, s2 = 0.f, s3 = 0.f;
    for (int p = 0; p < 256; p += 4) {
      s0 += col[(size_t)(p + 0) * 512];
      s1 += col[(size_t)(p + 1) * 512];
      s2 += col[(size_t)(p + 2) * 512];
      s3 += col[(size_t)(p + 3) * 512];
    }
    sxm[c] = ((s0 + s1) + (s2 + s3)) * (1.f / 256.f);
  }
  __syncthreads();
  if (part == 0) {
    float s0 = 0.f, s1 = 0.f, s2 = 0.f, s3 = 0.f;
#pragma unroll 4
    for (int e = 0; e < 256; e += 4) {
      s0 += sxm[e + 0] * Wsr[(e + 0) * 256 + d] - sxm[256 + e + 0] * Wsi[(e + 0) * 256 + d];
      s1 += sxm[e + 1] * Wsr[(e + 1) * 256 + d] - sxm[256 + e + 1] * Wsi[(e + 1) * 256 + d];
      s2 += sxm[e + 2] * Wsr[(e + 2) * 256 + d] - sxm[256 + e + 2] * Wsi[(e + 2) * 256 + d];
      s3 += sxm[e + 3] * Wsr[(e + 3) * 256 + d] - sxm[256 + e + 3] * Wsi[(e + 3) * 256 + d];
    }
    srcs[t * 512 + d] = (s0 + s1) + (s2 + s3);
  } else if (part == 1) {
    float s0 = 0.f, s1 = 0.f, s2 = 0.f, s3 = 0.f;
#pragma unroll 4
    for (int e = 0; e < 256; e += 4) {
      s0 += sxm[e + 0] * Wsi[(e + 0) * 256 + d] + sxm[256 + e + 0] * Wsr[(e + 0) * 256 + d];
      s1 += sxm[e + 1] * Wsi[(e + 1) * 256 + d] + sxm[256 + e + 1] * Wsr[(e + 1) * 256 + d];
      s2 += sxm[e + 2] * Wsi[(e + 2) * 256 + d] + sxm[256 + e + 2] * Wsr[(e + 2) * 256 + d];
      s3 += sxm[e + 3] * Wsi[(e + 3) * 256 + d] + sxm[256 + e + 3] * Wsr[(e + 3) * 256 + d];
    }
    srcs[t * 512 + 256 + d] = (s0 + s1) + (s2 + s3);
  } else {
    float s0 = 0.f, s1 = 0.f, s2 = 0.f, s3 = 0.f;
#pragma unroll 4
    for (int c = 0; c < 512; c += 4) {
      s0 += sxm[c + 0] * Wg[(c + 0) * 256 + d];
      s1 += sxm[c + 1] * Wg[(c + 1) * 256 + d];
      s2 += sxm[c + 2] * Wg[(c + 2) * 256 + d];
      s3 += sxm[c + 3] * Wg[(c + 3) * 256 + d];
    }
    const float ga = (s0 + s1) + (s2 + s3) + bg[d];
    gts[t * 256 + d] = 1.f / (1.f + expf(-ga));
  }
}

// Per-(p,d) time scan; opd/opf computed inline; FIRST => hprev == 0.
template <bool FIRST>
__global__ __launch_bounds__(256) void time_scan_k(
    const float* __restrict__ xe, const float* __restrict__ gts,
    const float* __restrict__ srcs, const float* __restrict__ lamre,
    const float* __restrict__ lamim, const float* __restrict__ dt,
    bf16* __restrict__ hout16, float* __restrict__ hprev) {
  const int d = threadIdx.x;
  const int p = blockIdx.x;
  const float lr0 = lamre[d];
  const float sp = (lr0 > 20.f) ? lr0 : log1pf(expf(lr0));
  const float lre = -(sp + 0.01f);
  const float lim = lamim[d];
  const float den = lre * lre + lim * lim;
  float ar[8], ai[8], ofr[8], ofi[8];
#pragma unroll
  for (int t = 0; t < 8; t++) {
    const float dtv = dt[t];
    const float er = expf(lre * dtv);
    const float odr = er * cosf(lim * dtv);
    const float odi = er * sinf(lim * dtv);
    ar[t] = odr;
    ai[t] = odi;
    const float nr = odr - 1.f, ni = odi;
    ofr[t] = (nr * lre + ni * lim) / den;
    ofi[t] = (ni * lre - nr * lim) / den;
  }
  float hr = 0.f, hi = 0.f;
  float hpr = 0.f, hpi = 0.f;
  if constexpr (!FIRST) {
    hpr = hprev[p * 512 + d];
    hpi = hprev[p * 512 + 256 + d];
  }
  float o7r = 0.f, o7i = 0.f;
#pragma unroll
  for (int t = 0; t < 8; t++) {
    const size_t base = (size_t)((t << 8) + p) * 512;
    const float xr = xe[base + d], xi = xe[base + 256 + d];
    const float g = gts[t * 256 + d];
    const float sr = srcs[t * 512 + d], si = srcs[t * 512 + 256 + d];
    const float fr = xr * g + sr * (1.f - g);
    const float fi = xi * g + si * (1.f - g);
    const float ur = fr * ofr[t] - fi * ofi[t];
    const float ui = fr * ofi[t] + fi * ofr[t];
    const float nhr = ur + ar[t] * hr - ai[t] * hi;
    const float nhi = ui + ar[t] * hi + ai[t] * hr;
    hr = nhr;
    hi = nhi;
    const float outr = hr + ar[t] * hpr - ai[t] * hpi;
    const float outi = hi + ar[t] * hpi + ai[t] * hpr;
    hout16[base + d] = (bf16)outr;
    hout16[base + 256 + d] = (bf16)outi;
    if (t == 7) {
      o7r = outr;
      o7i = outi;
    }
  }
  hprev[p * 512 + d] = o7r;
  hprev[p * 512 + 256 + d] = o7i;
}

extern "C" void kernel_launch(void* const* d_in, const int* in_sizes, int n_in,
                              void* d_out, int out_size, void* d_ws,
                              size_t ws_size, hipStream_t stream) {
  const float* x_in = (const float*)d_in[0];
  const float* dt = (const float*)d_in[1];
  const float* Wenc = (const float*)d_in[2];
  const float* benc = (const float*)d_in[3];
  const float* Wdec = (const float*)d_in[4];
  const float* bdec = (const float*)d_in[5];
  const float* ln_sp_w = (const float*)d_in[6];
  const float* ln_sp_b = (const float*)d_in[7];
  const float* conv_w = (const float*)d_in[8];
  const float* conv_b = (const float*)d_in[9];
  const float* E_re = (const float*)d_in[10];
  const float* E_im = (const float*)d_in[11];
  const float* Ed_re = (const float*)d_in[12];
  const float* Ed_im = (const float*)d_in[13];
  const float* Ws_re = (const float*)d_in[14];
  const float* Ws_im = (const float*)d_in[15];
  const float* Wg = (const float*)d_in[16];
  const float* bg = (const float*)d_in[17];
  const float* lam_re = (const float*)d_in[18];
  const float* lam_im = (const float*)d_in[19];
  const float* ln_t_w = (const float*)d_in[20];
  const float* ln_t_b = (const float*)d_in[21];
  const float* Wr = (const float*)d_in[22];
  const float* W1 = (const float*)d_in[23];
  const float* W2 = (const float*)d_in[24];
  float* out = (float*)d_out;

  float* ws = (float*)d_ws;
  size_t off = 0;
  auto allocf = [&](size_t n) {
    float* p = ws + off;
    off += n;
    return p;
  };
  auto allocb = [&](size_t n) {
    bf16* p = (bf16*)(ws + off);
    off += n / 2;
    return p;
  };
  float* z = allocf((size_t)TOKS * 512);
  float* zn = allocf((size_t)TOKS * 512);
  float* xb = allocf((size_t)TOKS * 512);
  float* xe = allocf((size_t)TOKS * 512);
  float* parts = allocf((size_t)4 * TOKS * 512);
  float* hprev = allocf(256 * 512);
  float* srcs = allocf(8 * 512);
  float* gts = allocf(8 * 256);
  float* probs = allocf((size_t)TOKS * 4);
  bf16* zn16 = allocb((size_t)TOKS * 512);
  bf16* xb16 = allocb((size_t)TOKS * 512);
  bf16* z16 = allocb((size_t)TOKS * 512);
  bf16* hb16 = allocb((size_t)TOKS * 512);
  bf16* hid16 = allocb((size_t)TOKS * 4096);
  bf16* Aenc16 = allocb((size_t)TOKS * 1024);
  bf16* WencT = allocb((size_t)512 * 1024);
  bf16* WdecT = allocb((size_t)1024 * 512);
  bf16* MEt = allocb((size_t)4 * 512 * 512);
  bf16* convBt = allocb((size_t)2 * 512 * 4608);
  bf16* W1T = allocb((size_t)8 * 1024 * 512);
  bf16* W2Tc = allocb((size_t)2 * 512 * 4096);

  // ---- all conversions in one launch ----
  cvt_all_k<<<18944, 256, 0, stream>>>(x_in, Wenc, Wdec, W1, W2, E_re, E_im,
                                       Ed_re, Ed_im, conv_w, Aenc16, WencT,
                                       WdecT, W1T, W2Tc, MEt, convBt);

  // ---- encoder ----
  mgemm_k<EENC><<<dim3(32, 8), 256, 0, stream>>>(Aenc16, WencT, benc, z, 1024,
                                                 512);

  for (int l = 0; l < 2; l++) {
    ln_k<false><<<512, 256, 0, stream>>>(z, ln_sp_w + l * 512,
                                         ln_sp_b + l * 512, nullptr, zn, zn16,
                                         nullptr);
    mgemm2_k<ECONV, 4><<<dim3(16, 4, 4), 256, 0, stream>>>(
        zn16, convBt + (size_t)l * 512 * 4608, nullptr, nullptr, parts, 4608,
        512);
    conv_ep_k<<<1024, 256, 0, stream>>>(parts, conv_b + l * 512, z, xb, xb16);
    mgemm_k<ESQ><<<dim3(32, 8), 256, 0, stream>>>(
        xb16, MEt + (size_t)(l * 2) * 262144, nullptr, xe, 512, 512);
    srcgate_k<<<dim3(8, 3), 256, 0, stream>>>(xe, Ws_re + l * 65536,
                                              Ws_im + l * 65536,
                                              Wg + l * 131072, bg + l * 256,
                                              srcs, gts);
    if (l == 0)
      time_scan_k<true><<<256, 256, 0, stream>>>(
          xe, gts, srcs, lam_re, lam_im, dt, hb16, hprev);
    else
      time_scan_k<false><<<256, 256, 0, stream>>>(
          xe, gts, srcs, lam_re + 256, lam_im + 256, dt, hb16, hprev);
    mgemm_k<ESQ><<<dim3(32, 8), 256, 0, stream>>>(
        hb16, MEt + (size_t)(l * 2 + 1) * 262144, nullptr, xe, 512, 512);
    ln_k<true><<<512, 256, 0, stream>>>(xe, ln_t_w + l * 512, ln_t_b + l * 512,
                                        Wr + l * 2048, zn, zn16, probs);
    mgemm2_k<EMOE1, 1><<<dim3(16, 8, 4), 256, 0, stream>>>(
        zn16, W1T + (size_t)l * 2097152, probs, hid16, nullptr, 512, 1024);
    mgemm2_k<EMOE2, 4><<<dim3(16, 4, 4), 256, 0, stream>>>(
        hid16, W2Tc + (size_t)l * 2097152, nullptr, nullptr, parts, 4096, 512);
    addf_k<<<1024, 256, 0, stream>>>(xb, zn, parts, z, z16);
  }

  // ---- decoder ----
  mgemm_k<EDEC><<<dim3(32, 16), 256, 0, stream>>>(z16, WdecT, bdec, out, 512,
                                                  1024);
}

// Round 7
// 478.518 us; speedup vs baseline: 4.4384x; 1.0347x over previous
//
#include <hip/hip_runtime.h>
#include <hip/hip_bf16.h>

// ---------------------------------------------------------------------------
// UniPhyModel: B=1 T=8 C=4 IH=IW=256 P=16 -> HP=WP=16, D=256 (2D=512), L=2,
// NE=4, FF=1024.  Token n = t*256 + hp*16 + wp (2048 tokens), channel
// c in [0,512): c<256 real, c>=256 imag.
// All GEMMs: 64x64-tile bf16 MFMA 16x16x32, register-prefetch, split-K so
// every grid >= 512 blocks (>=2 blocks/CU).  Split combines are folded into
// the consumers (LN / srcgate / tscan / conv_ep / addf) -> no extra passes.
// flux recurrence deleted (dead w.r.t. output).
// ---------------------------------------------------------------------------

#define TOKS 2048
#define PSLICE 1048576  // partial slice stride (2048*512 fp32)

typedef __bf16 bf16;
typedef __attribute__((ext_vector_type(8))) __bf16 bf16x8;
typedef __attribute__((ext_vector_type(4))) __bf16 bf16x4;
typedef __attribute__((ext_vector_type(4))) float f32x4;

enum GMode { EENC = 0, ECONV, ESQ, EMOE1, EMOE2, EDEC };

// ---------- 64x64 tile GEMM (4 waves, each 32x32 = 2x2 frags) ----------
// SPLIT>1: blockIdx.z = K-slice -> fp32 partials (N must be 512).
// EMOE1: blockIdx.z = expert; gelu*probs epilogue, C16 row stride 4096.
template <int MODE, int SPLIT>
__global__ __launch_bounds__(256) void mgemm_k(
    const bf16* __restrict__ A, const bf16* __restrict__ Bt,
    const float* __restrict__ bias, const float* __restrict__ scalev,
    float* __restrict__ C, bf16* __restrict__ C16, float* __restrict__ Cpart,
    int K, int N) {
  __shared__ __align__(16) bf16 As[64 * 40];
  __shared__ __align__(16) bf16 Bs[64 * 40];
  const int tid = threadIdx.x;
  const int bm = blockIdx.x * 64, bn = blockIdx.y * 64;
  const int lane = tid & 63, w = tid >> 6;
  const int wm = (w & 1) * 32, wn = (w >> 1) * 32;
  const int quad = lane >> 4, l16 = lane & 15;
  const int srow = tid >> 2, sko = (tid & 3) << 3;

  const int kbase = (SPLIT > 1) ? blockIdx.z * (K / SPLIT) : 0;
  const int kiter = K / (32 * SPLIT);
  if constexpr (MODE == EMOE1) Bt += (size_t)blockIdx.z * 524288;

  f32x4 acc[2][2] = {};

  int cv_t = 0, cv_h = 0, cv_w = 0;
  if constexpr (MODE == ECONV) {
    const int gm = bm + srow;
    cv_t = gm >> 8;
    cv_h = (gm >> 4) & 15;
    cv_w = gm & 15;
  }

  auto loadA = [&](int kt) -> bf16x8 {
    const int gk = kbase + kt * 32 + sko;
    if constexpr (MODE == ECONV) {
      const int s = gk >> 9, ci = gk & 511;  // 8-chunk never crosses s
      const int kh = s / 3, kw = s - kh * 3;
      const int hh = cv_h + kh - 1, ww = cv_w + kw - 1;
      if (hh >= 0 && hh < 16 && ww >= 0 && ww < 16)
        return *(const bf16x8*)&A[(size_t)(((cv_t << 8) + hh * 16 + ww) << 9) +
                                  ci];
      bf16x8 zz;
#pragma unroll
      for (int q = 0; q < 8; q++) zz[q] = (bf16)0.0f;
      return zz;
    } else {
      return *(const bf16x8*)&A[(size_t)(bm + srow) * K + gk];
    }
  };
  auto loadB = [&](int kt) -> bf16x8 {
    return *(const bf16x8*)&Bt[(size_t)(bn + srow) * K + kbase + kt * 32 + sko];
  };

  bf16x8 pa = loadA(0), pb = loadB(0);
  for (int kt = 0; kt < kiter; kt++) {
    *(bf16x8*)&As[srow * 40 + sko] = pa;
    *(bf16x8*)&Bs[srow * 40 + sko] = pb;
    __syncthreads();
    if (kt + 1 < kiter) {
      pa = loadA(kt + 1);
      pb = loadB(kt + 1);
    }
    const bf16x8 a0 = *(const bf16x8*)&As[(wm + l16) * 40 + quad * 8];
    const bf16x8 a1 = *(const bf16x8*)&As[(wm + 16 + l16) * 40 + quad * 8];
    const bf16x8 b0 = *(const bf16x8*)&Bs[(wn + l16) * 40 + quad * 8];
    const bf16x8 b1 = *(const bf16x8*)&Bs[(wn + 16 + l16) * 40 + quad * 8];
    acc[0][0] = __builtin_amdgcn_mfma_f32_16x16x32_bf16(a0, b0, acc[0][0], 0, 0, 0);
    acc[0][1] = __builtin_amdgcn_mfma_f32_16x16x32_bf16(a0, b1, acc[0][1], 0, 0, 0);
    acc[1][0] = __builtin_amdgcn_mfma_f32_16x16x32_bf16(a1, b0, acc[1][0], 0, 0, 0);
    acc[1][1] = __builtin_amdgcn_mfma_f32_16x16x32_bf16(a1, b1, acc[1][1], 0, 0, 0);
    __syncthreads();
  }

  // epilogue; C/D layout: col = lane&15, row = quad*4 + reg
#pragma unroll
  for (int i = 0; i < 2; i++) {
#pragma unroll
    for (int j = 0; j < 2; j++) {
#pragma unroll
      for (int r = 0; r < 4; r++) {
        const int gm = bm + wm + i * 16 + quad * 4 + r;
        const int gn = bn + wn + j * 16 + l16;
        const float v = acc[i][j][r];
        if constexpr (SPLIT > 1) {
          Cpart[(size_t)blockIdx.z * PSLICE + (size_t)gm * 512 + gn] = v;
        } else if constexpr (MODE == EMOE1) {
          const float t = 0.7978845608028654f * (v + 0.044715f * v * v * v);
          const float g = 0.5f * v * (1.f + tanhf(t));
          const float p = scalev[gm * 4 + blockIdx.z];
          C16[(size_t)gm * 4096 + blockIdx.z * 1024 + gn] = (bf16)(p * g);
        } else {  // EDEC: scatter to (B,T,C,IH,IW)
          const int t = gm >> 8, hp = (gm >> 4) & 15, wp = gm & 15;
          const int c = gn >> 8, ph = (gn >> 4) & 15, pw = gn & 15;
          C[(size_t)(((t * 4 + c) * 256 + hp * 16 + ph) << 8) + wp * 16 + pw] =
              v + bias[gn];
        }
      }
    }
  }
}

// conv combine: xb = sum(4 partials) + bias + residual z; fp32 + bf16 out.
__global__ __launch_bounds__(256) void conv_ep_k(
    const float* __restrict__ parts, const float* __restrict__ bias,
    const float* __restrict__ resid, float* __restrict__ xb,
    bf16* __restrict__ xb16) {
  const int i4 = (blockIdx.x * 256 + threadIdx.x) << 2;
  const int c = i4 & 511;
  const float4 p0 = *(const float4*)&parts[i4];
  const float4 p1 = *(const float4*)&parts[PSLICE + i4];
  const float4 p2 = *(const float4*)&parts[2 * PSLICE + i4];
  const float4 p3 = *(const float4*)&parts[3 * PSLICE + i4];
  const float4 bi = *(const float4*)&bias[c];
  const float4 rz = *(const float4*)&resid[i4];
  float4 o;
  o.x = p0.x + p1.x + p2.x + p3.x + bi.x + rz.x;
  o.y = p0.y + p1.y + p2.y + p3.y + bi.y + rz.y;
  o.z = p0.z + p1.z + p2.z + p3.z + bi.z + rz.z;
  o.w = p0.w + p1.w + p2.w + p3.w + bi.w + rz.w;
  *(float4*)&xb[i4] = o;
  bf16x4 o16 = {(bf16)o.x, (bf16)o.y, (bf16)o.z, (bf16)o.w};
  *(bf16x4*)&xb16[i4] = o16;
}

// LN over 512 channels of (p0+p1 [+bias]); one wave/token, 4 tokens/block.
// ENC: +bias, write raw z fp32, LN -> bf16 only.
// !ENC: no bias, LN -> fp32 + bf16, plus probs = softmax(ln @ Wr).
template <bool ENC>
__global__ __launch_bounds__(256) void ln_comb_k(
    const float* __restrict__ parts, const float* __restrict__ bias,
    const float* __restrict__ w, const float* __restrict__ b,
    const float* __restrict__ Wr, float* __restrict__ zout,
    float* __restrict__ out32, bf16* __restrict__ out16,
    float* __restrict__ probs) {
  const int wv = threadIdx.x >> 6, lane = threadIdx.x & 63;
  const int n = (blockIdx.x << 2) + wv;
  float v[8];
  float s = 0.f, s2 = 0.f;
#pragma unroll
  for (int i = 0; i < 8; i++) {
    const int c = (i << 6) + lane;
    float x = parts[(size_t)n * 512 + c] + parts[PSLICE + (size_t)n * 512 + c];
    if constexpr (ENC) x += bias[c];
    v[i] = x;
    s += x;
    s2 += x * x;
  }
#pragma unroll
  for (int off = 32; off > 0; off >>= 1) {
    s += __shfl_down(s, off);
    s2 += __shfl_down(s2, off);
  }
  s = __shfl(s, 0);
  s2 = __shfl(s2, 0);
  const float m = s * (1.f / 512.f);
  const float var = s2 * (1.f / 512.f) - m * m;
  const float r = rsqrtf(var + 1e-5f);
  float a0 = 0.f, a1 = 0.f, a2 = 0.f, a3 = 0.f;
#pragma unroll
  for (int i = 0; i < 8; i++) {
    const int c = (i << 6) + lane;
    const float o = (v[i] - m) * r * w[c] + b[c];
    if constexpr (ENC) {
      zout[(size_t)n * 512 + c] = v[i];
    } else {
      out32[(size_t)n * 512 + c] = o;
      a0 += o * Wr[c * 4 + 0];
      a1 += o * Wr[c * 4 + 1];
      a2 += o * Wr[c * 4 + 2];
      a3 += o * Wr[c * 4 + 3];
    }
    out16[(size_t)n * 512 + c] = (bf16)o;
  }
  if constexpr (!ENC) {
#pragma unroll
    for (int off = 32; off > 0; off >>= 1) {
      a0 += __shfl_down(a0, off);
      a1 += __shfl_down(a1, off);
      a2 += __shfl_down(a2, off);
      a3 += __shfl_down(a3, off);
    }
    if (lane == 0) {
      const float mx = fmaxf(fmaxf(a0, a1), fmaxf(a2, a3));
      const float e0 = expf(a0 - mx), e1 = expf(a1 - mx), e2 = expf(a2 - mx),
                  e3 = expf(a3 - mx);
      const float inv = 1.f / (e0 + e1 + e2 + e3);
      probs[n * 4 + 0] = e0 * inv;
      probs[n * 4 + 1] = e1 * inv;
      probs[n * 4 + 2] = e2 * inv;
      probs[n * 4 + 3] = e3 * inv;
    }
  }
}

// final residual v = xb + xn + sum(4 MoE2 partials).
// DO_LN: write z fp32 + LN(ln_sp next layer) -> znsp16.  else: z16 = bf16(v).
template <bool DO_LN>
__global__ __launch_bounds__(256) void addf2_k(
    const float* __restrict__ xb, const float* __restrict__ xn,
    const float* __restrict__ parts, const float* __restrict__ w,
    const float* __restrict__ b, float* __restrict__ zout,
    bf16* __restrict__ out16) {
  const int wv = threadIdx.x >> 6, lane = threadIdx.x & 63;
  const int n = (blockIdx.x << 2) + wv;
  float v[8];
  float s = 0.f, s2 = 0.f;
#pragma unroll
  for (int i = 0; i < 8; i++) {
    const size_t idx = (size_t)n * 512 + (i << 6) + lane;
    const float x = xb[idx] + xn[idx] + parts[idx] + parts[PSLICE + idx] +
                    parts[2 * PSLICE + idx] + parts[3 * PSLICE + idx];
    v[i] = x;
    s += x;
    s2 += x * x;
  }
  if constexpr (!DO_LN) {
#pragma unroll
    for (int i = 0; i < 8; i++)
      out16[(size_t)n * 512 + (i << 6) + lane] = (bf16)v[i];
    return;
  }
#pragma unroll
  for (int off = 32; off > 0; off >>= 1) {
    s += __shfl_down(s, off);
    s2 += __shfl_down(s2, off);
  }
  s = __shfl(s, 0);
  s2 = __shfl(s2, 0);
  const float m = s * (1.f / 512.f);
  const float var = s2 * (1.f / 512.f) - m * m;
  const float r = rsqrtf(var + 1e-5f);
#pragma unroll
  for (int i = 0; i < 8; i++) {
    const int c = (i << 6) + lane;
    const float x = v[i];
    zout[(size_t)n * 512 + c] = x;
    out16[(size_t)n * 512 + c] = (bf16)((x - m) * r * w[c] + b[c]);
  }
}

// ---------- merged conversions: one launch, block-range decode ----------
// [0,1024): enc patches  [1024,1536): Wenc^T  [1536,2048): Wdec^T
// [2048,6144): W1^T(8)   [6144,10240): W2->W2Tc(8)
// [10240,14336): MEt(4)  [14336,15360): convBt (per (l,co), LDS staged)
__global__ __launch_bounds__(256) void cvt_all_k(
    const float* __restrict__ x, const float* __restrict__ Wenc,
    const float* __restrict__ Wdec, const float* __restrict__ W1,
    const float* __restrict__ W2, const float* __restrict__ E_re,
    const float* __restrict__ E_im, const float* __restrict__ Ed_re,
    const float* __restrict__ Ed_im, const float* __restrict__ conv_w,
    bf16* __restrict__ Ae, bf16* __restrict__ WencT, bf16* __restrict__ WdecT,
    bf16* __restrict__ W1T, bf16* __restrict__ W2Tc, bf16* __restrict__ MEt,
    bf16* __restrict__ convBt) {
  __shared__ float smem[4608];
  float(*tile)[33] = (float(*)[33])smem;
  const int tid = threadIdx.x;
  int b = blockIdx.x;
  const int tx = tid & 31, ty = tid >> 5;
  auto tpose = [&](const float* src, bf16* dst, int N, int dstride, int k0,
                   int n0) {
#pragma unroll
    for (int r = 0; r < 4; r++)
      tile[ty + 8 * r][tx] = src[(size_t)(k0 + ty + 8 * r) * N + n0 + tx];
    __syncthreads();
#pragma unroll
    for (int r = 0; r < 4; r++)
      dst[(size_t)(n0 + ty + 8 * r) * dstride + k0 + tx] =
          (bf16)tile[tx][ty + 8 * r];
  };
  if (b < 1024) {  // encoder patch gather + cast
    const int id = b * 256 + tid;
    const int n = id >> 7;
    const int kc = (id & 127) << 3;
    const int t = n >> 8, hp = (n >> 4) & 15, wp = n & 15;
    const int c = kc >> 8, ph = (kc >> 4) & 15, pw = kc & 15;
    const float* src =
        &x[(size_t)(((t * 4 + c) * 256 + hp * 16 + ph) << 8) + wp * 16 + pw];
    const float4 v0 = *(const float4*)src;
    const float4 v1 = *(const float4*)(src + 4);
    bf16* d = &Ae[(size_t)n * 1024 + kc];
    d[0] = (bf16)v0.x; d[1] = (bf16)v0.y; d[2] = (bf16)v0.z; d[3] = (bf16)v0.w;
    d[4] = (bf16)v1.x; d[5] = (bf16)v1.y; d[6] = (bf16)v1.z; d[7] = (bf16)v1.w;
    return;
  }
  b -= 1024;
  if (b < 512) {  // Wenc [1024][512] -> [512][1024]
    tpose(Wenc, WencT, 512, 1024, (b & 31) * 32, (b >> 5) * 32);
    return;
  }
  b -= 512;
  if (b < 512) {  // Wdec [512][1024] -> [1024][512]
    tpose(Wdec, WdecT, 1024, 512, (b & 15) * 32, (b >> 4) * 32);
    return;
  }
  b -= 512;
  if (b < 4096) {  // W1 (8)[512][1024] -> [1024][512]
    const int z = b >> 9, rem = b & 511;
    tpose(W1 + (size_t)z * 524288, W1T + (size_t)z * 524288, 1024, 512,
          (rem & 15) * 32, (rem >> 4) * 32);
    return;
  }
  b -= 4096;
  if (b < 4096) {  // W2 (l,e)[1024][512] -> W2Tc[l][512][e*1024+k]
    const int z = b >> 9, rem = b & 511;
    const int l = z >> 2, e = z & 3;
    tpose(W2 + (size_t)z * 524288, W2Tc + (size_t)l * 2097152 + e * 1024, 512,
          4096, (rem & 31) * 32, (rem >> 5) * 32);
    return;
  }
  b -= 4096;
  if (b < 4096) {  // MEt[z][j=512][k=512] = [[Er,Ei],[-Ei,Er]]^T
    const int z = b >> 10;
    const int l = z >> 1, which = z & 1;
    const float* Er = (which ? Ed_re : E_re) + l * 65536;
    const float* Ei = (which ? Ed_im : E_im) + l * 65536;
    bf16* dst = MEt + (size_t)z * 262144;
    const int idx = (b & 1023) * 256 + tid;
    const int j = idx >> 9, k = idx & 511;
    const int kk = k & 255, jj = j & 255;
    const float er = Er[kk * 256 + jj], ei = Ei[kk * 256 + jj];
    const float v = (k < 256) ? ((j < 256) ? er : ei) : ((j < 256) ? -ei : er);
    dst[idx] = (bf16)v;
    return;
  }
  b -= 4096;
  {  // conv_w: one block per (l,co); coalesced read -> LDS -> coalesced write
    const int l = b >> 9, co = b & 511;
    const float* src = conv_w + (size_t)l * 2359296 + (size_t)co * 4608;
    bf16* d = convBt + (size_t)l * 2359296 + (size_t)co * 4608;
    for (int i = tid; i < 4608; i += 256) smem[i] = src[i];
    __syncthreads();
    for (int o = tid; o < 4608; o += 256) {
      const int s = o >> 9, ci = o & 511;
      d[o] = (bf16)smem[ci * 9 + s];
    }
  }
}

// Parallel src/gate with fused spatial mean over esq1 partials (2 slices).
__global__ __launch_bounds__(256) void srcgate_k(
    const float* __restrict__ parts, const float* __restrict__ Wsr,
    const float* __restrict__ Wsi, const float* __restrict__ Wg,
    const float* __restrict__ bg, float* __restrict__ srcs,
    float* __restrict__ gts) {
  const int t = blockIdx.x, part = blockIdx.y, d = threadIdx.x;
  __shared__ float sxm[512];
  for (int c = d; c < 512; c += 256) {
    const float* col0 = parts + (size_t)(t << 8) * 512 + c;
    const float* col1 = col0 + PSLICE;
    float s0 = 0.f, s1 = 0.f;
    for (int p = 0; p < 256; p += 2) {
      s0 += col0[(size_t)p * 512] + col1[(size_t)p * 512];
      s1 += col0[(size_t)(p + 1) * 512] + col1[(size_t)(p + 1) * 512];
    }
    sxm[c] = (s0 + s1) * (1.f / 256.f);
  }
  __syncthreads();
  if (part == 0) {
    float s0 = 0.f, s1 = 0.f, s2 = 0.f, s3 = 0.f;
#pragma unroll 4
    for (int e = 0; e < 256; e += 4) {
      s0 += sxm[e + 0] * Wsr[(e + 0) * 256 + d] - sxm[256 + e + 0] * Wsi[(e + 0) * 256 + d];
      s1 += sxm[e + 1] * Wsr[(e + 1) * 256 + d] - sxm[256 + e + 1] * Wsi[(e + 1) * 256 + d];
      s2 += sxm[e + 2] * Wsr[(e + 2) * 256 + d] - sxm[256 + e + 2] * Wsi[(e + 2) * 256 + d];
      s3 += sxm[e + 3] * Wsr[(e + 3) * 256 + d] - sxm[256 + e + 3] * Wsi[(e + 3) * 256 + d];
    }
    srcs[t * 512 + d] = (s0 + s1) + (s2 + s3);
  } else if (part == 1) {
    float s0 = 0.f, s1 = 0.f, s2 = 0.f, s3 = 0.f;
#pragma unroll 4
    for (int e = 0; e < 256; e += 4) {
      s0 += sxm[e + 0] * Wsi[(e + 0) * 256 + d] + sxm[256 + e + 0] * Wsr[(e + 0) * 256 + d];
      s1 += sxm[e + 1] * Wsi[(e + 1) * 256 + d] + sxm[256 + e + 1] * Wsr[(e + 1) * 256 + d];
      s2 += sxm[e + 2] * Wsi[(e + 2) * 256 + d] + sxm[256 + e + 2] * Wsr[(e + 2) * 256 + d];
      s3 += sxm[e + 3] * Wsi[(e + 3) * 256 + d] + sxm[256 + e + 3] * Wsr[(e + 3) * 256 + d];
    }
    srcs[t * 512 + 256 + d] = (s0 + s1) + (s2 + s3);
  } else {
    float s0 = 0.f, s1 = 0.f, s2 = 0.f, s3 = 0.f;
#pragma unroll 4
    for (int c = 0; c < 512; c += 4) {
      s0 += sxm[c + 0] * Wg[(c + 0) * 256 + d];
      s1 += sxm[c + 1] * Wg[(c + 1) * 256 + d];
      s2 += sxm[c + 2] * Wg[(c + 2) * 256 + d];
      s3 += sxm[c + 3] * Wg[(c + 3) * 256 + d];
    }
    const float ga = (s0 + s1) + (s2 + s3) + bg[d];
    gts[t * 256 + d] = 1.f / (1.f + expf(-ga));
  }
}

// Per-(p,d) time scan over esq1 partials (2 slices); opd/opf inline.
template <bool FIRST>
__global__ __launch_bounds__(256) void time_scan_k(
    const float* __restrict__ parts, const float* __restrict__ gts,
    const float* __restrict__ srcs, const float* __restrict__ lamre,
    const float* __restrict__ lamim, const float* __restrict__ dt,
    bf16* __restrict__ hout16, float* __restrict__ hprev) {
  const int d = threadIdx.x;
  const int p = blockIdx.x;
  const float lr0 = lamre[d];
  const float sp = (lr0 > 20.f) ? lr0 : log1pf(expf(lr0));
  const float lre = -(sp + 0.01f);
  const float lim = lamim[d];
  const float den = lre * lre + lim * lim;
  float ar[8], ai[8], ofr[8], ofi[8];
#pragma unroll
  for (int t = 0; t < 8; t++) {
    const float dtv = dt[t];
    const float er = expf(lre * dtv);
    const float odr = er * cosf(lim * dtv);
    const float odi = er * sinf(lim * dtv);
    ar[t] = odr;
    ai[t] = odi;
    const float nr = odr - 1.f, ni = odi;
    ofr[t] = (nr * lre + ni * lim) / den;
    ofi[t] = (ni * lre - nr * lim) / den;
  }
  float hr = 0.f, hi = 0.f;
  float hpr = 0.f, hpi = 0.f;
  if constexpr (!FIRST) {
    hpr = hprev[p * 512 + d];
    hpi = hprev[p * 512 + 256 + d];
  }
  float o7r = 0.f, o7i = 0.f;
#pragma unroll
  for (int t = 0; t < 8; t++) {
    const size_t base = (size_t)((t << 8) + p) * 512;
    const float xr = parts[base + d] + parts[PSLICE + base + d];
    const float xi = parts[base + 256 + d] + parts[PSLICE + base + 256 + d];
    const float g = gts[t * 256 + d];
    const float sr = srcs[t * 512 + d], si = srcs[t * 512 + 256 + d];
    const float fr = xr * g + sr * (1.f - g);
    const float fi = xi * g + si * (1.f - g);
    const float ur = fr * ofr[t] - fi * ofi[t];
    const float ui = fr * ofi[t] + fi * ofr[t];
    const float nhr = ur + ar[t] * hr - ai[t] * hi;
    const float nhi = ui + ar[t] * hi + ai[t] * hr;
    hr = nhr;
    hi = nhi;
    const float outr = hr + ar[t] * hpr - ai[t] * hpi;
    const float outi = hi + ar[t] * hpi + ai[t] * hpr;
    hout16[base + d] = (bf16)outr;
    hout16[base + 256 + d] = (bf16)outi;
    if (t == 7) {
      o7r = outr;
      o7i = outi;
    }
  }
  hprev[p * 512 + d] = o7r;
  hprev[p * 512 + 256 + d] = o7i;
}

extern "C" void kernel_launch(void* const* d_in, const int* in_sizes, int n_in,
                              void* d_out, int out_size, void* d_ws,
                              size_t ws_size, hipStream_t stream) {
  const float* x_in = (const float*)d_in[0];
  const float* dt = (const float*)d_in[1];
  const float* Wenc = (const float*)d_in[2];
  const float* benc = (const float*)d_in[3];
  const float* Wdec = (const float*)d_in[4];
  const float* bdec = (const float*)d_in[5];
  const float* ln_sp_w = (const float*)d_in[6];
  const float* ln_sp_b = (const float*)d_in[7];
  const float* conv_w = (const float*)d_in[8];
  const float* conv_b = (const float*)d_in[9];
  const float* E_re = (const float*)d_in[10];
  const float* E_im = (const float*)d_in[11];
  const float* Ed_re = (const float*)d_in[12];
  const float* Ed_im = (const float*)d_in[13];
  const float* Ws_re = (const float*)d_in[14];
  const float* Ws_im = (const float*)d_in[15];
  const float* Wg = (const float*)d_in[16];
  const float* bg = (const float*)d_in[17];
  const float* lam_re = (const float*)d_in[18];
  const float* lam_im = (const float*)d_in[19];
  const float* ln_t_w = (const float*)d_in[20];
  const float* ln_t_b = (const float*)d_in[21];
  const float* Wr = (const float*)d_in[22];
  const float* W1 = (const float*)d_in[23];
  const float* W2 = (const float*)d_in[24];
  float* out = (float*)d_out;

  float* ws = (float*)d_ws;
  size_t off = 0;
  auto allocf = [&](size_t n) {
    float* p = ws + off;
    off += n;
    return p;
  };
  auto allocb = [&](size_t n) {
    bf16* p = (bf16*)(ws + off);
    off += n / 2;
    return p;
  };
  float* z = allocf((size_t)TOKS * 512);
  float* xn = allocf((size_t)TOKS * 512);
  float* xb = allocf((size_t)TOKS * 512);
  float* parts = allocf((size_t)4 * PSLICE);
  float* hprev = allocf(256 * 512);
  float* srcs = allocf(8 * 512);
  float* gts = allocf(8 * 256);
  float* probs = allocf((size_t)TOKS * 4);
  bf16* znsp16 = allocb((size_t)TOKS * 512);
  bf16* xn16 = allocb((size_t)TOKS * 512);
  bf16* xb16 = allocb((size_t)TOKS * 512);
  bf16* z16 = allocb((size_t)TOKS * 512);
  bf16* hb16 = allocb((size_t)TOKS * 512);
  bf16* hid16 = allocb((size_t)TOKS * 4096);
  bf16* Aenc16 = allocb((size_t)TOKS * 1024);
  bf16* WencT = allocb((size_t)512 * 1024);
  bf16* WdecT = allocb((size_t)1024 * 512);
  bf16* MEt = allocb((size_t)4 * 512 * 512);
  bf16* convBt = allocb((size_t)2 * 512 * 4608);
  bf16* W1T = allocb((size_t)8 * 1024 * 512);
  bf16* W2Tc = allocb((size_t)2 * 512 * 4096);

  // ---- all conversions in one launch ----
  cvt_all_k<<<15360, 256, 0, stream>>>(x_in, Wenc, Wdec, W1, W2, E_re, E_im,
                                       Ed_re, Ed_im, conv_w, Aenc16, WencT,
                                       WdecT, W1T, W2Tc, MEt, convBt);

  // ---- encoder: split-K=2, combine folded into LN ----
  mgemm_k<EENC, 2><<<dim3(32, 8, 2), 256, 0, stream>>>(
      Aenc16, WencT, nullptr, nullptr, nullptr, nullptr, parts, 1024, 512);
  ln_comb_k<true><<<512, 256, 0, stream>>>(parts, benc, ln_sp_w, ln_sp_b,
                                           nullptr, z, nullptr, znsp16,
                                           nullptr);

  for (int l = 0; l < 2; l++) {
    mgemm_k<ECONV, 4><<<dim3(32, 8, 4), 256, 0, stream>>>(
        znsp16, convBt + (size_t)l * 2359296, nullptr, nullptr, nullptr,
        nullptr, parts, 4608, 512);
    conv_ep_k<<<1024, 256, 0, stream>>>(parts, conv_b + l * 512, z, xb, xb16);
    mgemm_k<ESQ, 2><<<dim3(32, 8, 2), 256, 0, stream>>>(
        xb16, MEt + (size_t)(l * 2) * 262144, nullptr, nullptr, nullptr,
        nullptr, parts, 512, 512);
    srcgate_k<<<dim3(8, 3), 256, 0, stream>>>(parts, Ws_re + l * 65536,
                                              Ws_im + l * 65536,
                                              Wg + l * 131072, bg + l * 256,
                                              srcs, gts);
    if (l == 0)
      time_scan_k<true><<<256, 256, 0, stream>>>(parts, gts, srcs, lam_re,
                                                 lam_im, dt, hb16, hprev);
    else
      time_scan_k<false><<<256, 256, 0, stream>>>(parts, gts, srcs,
                                                  lam_re + 256, lam_im + 256,
                                                  dt, hb16, hprev);
    mgemm_k<ESQ, 2><<<dim3(32, 8, 2), 256, 0, stream>>>(
        hb16, MEt + (size_t)(l * 2 + 1) * 262144, nullptr, nullptr, nullptr,
        nullptr, parts, 512, 512);
    ln_comb_k<false><<<512, 256, 0, stream>>>(parts, nullptr, ln_t_w + l * 512,
                                              ln_t_b + l * 512, Wr + l * 2048,
                                              nullptr, xn, xn16, probs);
    mgemm_k<EMOE1, 1><<<dim3(32, 16, 4), 256, 0, stream>>>(
        xn16, W1T + (size_t)l * 2097152, nullptr, probs, nullptr, hid16,
        nullptr, 512, 1024);
    mgemm_k<EMOE2, 4><<<dim3(32, 8, 4), 256, 0, stream>>>(
        hid16, W2Tc + (size_t)l * 2097152, nullptr, nullptr, nullptr, nullptr,
        parts, 4096, 512);
    if (l == 0)
      addf2_k<true><<<512, 256, 0, stream>>>(xb, xn, parts, ln_sp_w + 512,
                                             ln_sp_b + 512, z, znsp16);
    else
      addf2_k<false><<<512, 256, 0, stream>>>(xb, xn, parts, nullptr, nullptr,
                                              nullptr, z16);
  }

  // ---- decoder ----
  mgemm_k<EDEC, 1><<<dim3(32, 16), 256, 0, stream>>>(
      z16, WdecT, bdec, nullptr, out, nullptr, nullptr, 512, 1024);
}

// Round 8
// 458.775 us; speedup vs baseline: 4.6294x; 1.0430x over previous
//
#include <hip/hip_runtime.h>
#include <hip/hip_bf16.h>

// ---------------------------------------------------------------------------
// UniPhyModel: B=1 T=8 C=4 IH=IW=256 P=16 -> HP=WP=16, D=256 (2D=512), L=2,
// NE=4, FF=1024.  Token n = t*256 + hp*16 + wp (2048 tokens), channel
// c in [0,512): c<256 real, c>=256 imag.
// All GEMMs: 64x64-tile bf16 MFMA 16x16x32, register prefetch, split-K for
// occupancy (conv/moe2: 8 slices -> 8 blocks/CU).  Split combines folded into
// consumers.  Spatial mean folded into esq1 epilogue via atomicAdd (kills
// srcgate's 1 MB/block strided re-read).  flux recurrence deleted (dead).
// ---------------------------------------------------------------------------

#define TOKS 2048
#define PSLICE 1048576  // partial slice stride (2048*512 fp32)

typedef __bf16 bf16;
typedef __attribute__((ext_vector_type(8))) __bf16 bf16x8;
typedef __attribute__((ext_vector_type(4))) __bf16 bf16x4;
typedef __attribute__((ext_vector_type(4))) float f32x4;

enum GMode { EENC = 0, ECONV, ESQ, ESQM, EMOE1, EMOE2, EDEC };

// ---------- 64x64 tile GEMM (4 waves, each 32x32 = 2x2 frags) ----------
// SPLIT>1: blockIdx.z = K-slice -> fp32 partials (N must be 512).
// ESQM: like ESQ but also atomicAdd per-column row-sums into xmean[t*512+c].
// EMOE1: blockIdx.z = expert; gelu*probs epilogue, C16 row stride 4096.
template <int MODE, int SPLIT>
__global__ __launch_bounds__(256) void mgemm_k(
    const bf16* __restrict__ A, const bf16* __restrict__ Bt,
    const float* __restrict__ bias, const float* __restrict__ scalev,
    float* __restrict__ C, bf16* __restrict__ C16, float* __restrict__ Cpart,
    float* __restrict__ xmean, int K, int N) {
  __shared__ __align__(16) bf16 As[64 * 40];
  __shared__ __align__(16) bf16 Bs[64 * 40];
  const int tid = threadIdx.x;
  const int bm = blockIdx.x * 64, bn = blockIdx.y * 64;
  const int lane = tid & 63, w = tid >> 6;
  const int wm = (w & 1) * 32, wn = (w >> 1) * 32;
  const int quad = lane >> 4, l16 = lane & 15;
  const int srow = tid >> 2, sko = (tid & 3) << 3;

  const int kbase = (SPLIT > 1) ? blockIdx.z * (K / SPLIT) : 0;
  const int kiter = K / (32 * SPLIT);
  if constexpr (MODE == EMOE1) Bt += (size_t)blockIdx.z * 524288;

  f32x4 acc[2][2] = {};

  int cv_t = 0, cv_h = 0, cv_w = 0;
  if constexpr (MODE == ECONV) {
    const int gm = bm + srow;
    cv_t = gm >> 8;
    cv_h = (gm >> 4) & 15;
    cv_w = gm & 15;
  }

  auto loadA = [&](int kt) -> bf16x8 {
    const int gk = kbase + kt * 32 + sko;
    if constexpr (MODE == ECONV) {
      const int s = gk >> 9, ci = gk & 511;  // 8-chunk never crosses s
      const int kh = s / 3, kw = s - kh * 3;
      const int hh = cv_h + kh - 1, ww = cv_w + kw - 1;
      if (hh >= 0 && hh < 16 && ww >= 0 && ww < 16)
        return *(const bf16x8*)&A[(size_t)(((cv_t << 8) + hh * 16 + ww) << 9) +
                                  ci];
      bf16x8 zz;
#pragma unroll
      for (int q = 0; q < 8; q++) zz[q] = (bf16)0.0f;
      return zz;
    } else {
      return *(const bf16x8*)&A[(size_t)(bm + srow) * K + gk];
    }
  };
  auto loadB = [&](int kt) -> bf16x8 {
    return *(const bf16x8*)&Bt[(size_t)(bn + srow) * K + kbase + kt * 32 + sko];
  };

  bf16x8 pa = loadA(0), pb = loadB(0);
  for (int kt = 0; kt < kiter; kt++) {
    *(bf16x8*)&As[srow * 40 + sko] = pa;
    *(bf16x8*)&Bs[srow * 40 + sko] = pb;
    __syncthreads();
    if (kt + 1 < kiter) {
      pa = loadA(kt + 1);
      pb = loadB(kt + 1);
    }
    const bf16x8 a0 = *(const bf16x8*)&As[(wm + l16) * 40 + quad * 8];
    const bf16x8 a1 = *(const bf16x8*)&As[(wm + 16 + l16) * 40 + quad * 8];
    const bf16x8 b0 = *(const bf16x8*)&Bs[(wn + l16) * 40 + quad * 8];
    const bf16x8 b1 = *(const bf16x8*)&Bs[(wn + 16 + l16) * 40 + quad * 8];
    acc[0][0] = __builtin_amdgcn_mfma_f32_16x16x32_bf16(a0, b0, acc[0][0], 0, 0, 0);
    acc[0][1] = __builtin_amdgcn_mfma_f32_16x16x32_bf16(a0, b1, acc[0][1], 0, 0, 0);
    acc[1][0] = __builtin_amdgcn_mfma_f32_16x16x32_bf16(a1, b0, acc[1][0], 0, 0, 0);
    acc[1][1] = __builtin_amdgcn_mfma_f32_16x16x32_bf16(a1, b1, acc[1][1], 0, 0, 0);
    __syncthreads();
  }

  // epilogue; C/D layout: col = lane&15, row = quad*4 + reg
#pragma unroll
  for (int i = 0; i < 2; i++) {
#pragma unroll
    for (int j = 0; j < 2; j++) {
#pragma unroll
      for (int r = 0; r < 4; r++) {
        const int gm = bm + wm + i * 16 + quad * 4 + r;
        const int gn = bn + wn + j * 16 + l16;
        const float v = acc[i][j][r];
        if constexpr (SPLIT > 1) {
          Cpart[(size_t)blockIdx.z * PSLICE + (size_t)gm * 512 + gn] = v;
        } else if constexpr (MODE == EMOE1) {
          const float t = 0.7978845608028654f * (v + 0.044715f * v * v * v);
          const float g = 0.5f * v * (1.f + tanhf(t));
          const float p = scalev[gm * 4 + blockIdx.z];
          C16[(size_t)gm * 4096 + blockIdx.z * 1024 + gn] = (bf16)(p * g);
        } else {  // EDEC: scatter to (B,T,C,IH,IW)
          const int t = gm >> 8, hp = (gm >> 4) & 15, wp = gm & 15;
          const int c = gn >> 8, ph = (gn >> 4) & 15, pw = gn & 15;
          C[(size_t)(((t * 4 + c) * 256 + hp * 16 + ph) << 8) + wp * 16 + pw] =
              v + bias[gn];
        }
      }
    }
  }
  if constexpr (MODE == ESQM) {
    // per-thread column sums over its 8 rows -> atomic into xmean[t*512+c]
    const int t = bm >> 8;  // 64-row tile lies within one t
#pragma unroll
    for (int j = 0; j < 2; j++) {
      float cs = 0.f;
#pragma unroll
      for (int i = 0; i < 2; i++)
#pragma unroll
        for (int r = 0; r < 4; r++) cs += acc[i][j][r];
      atomicAdd(&xmean[t * 512 + bn + wn + j * 16 + l16], cs);
    }
  }
}

// conv combine: xb = sum(8 partials) + bias + residual z; also zero xmean.
__global__ __launch_bounds__(256) void conv_ep_k(
    const float* __restrict__ parts, const float* __restrict__ bias,
    const float* __restrict__ resid, float* __restrict__ xb,
    bf16* __restrict__ xb16, float* __restrict__ xmean) {
  if (blockIdx.x < 16) xmean[blockIdx.x * 256 + threadIdx.x] = 0.f;
  const int i4 = (blockIdx.x * 256 + threadIdx.x) << 2;
  const int c = i4 & 511;
  float4 o = *(const float4*)&resid[i4];
  const float4 bi = *(const float4*)&bias[c];
  o.x += bi.x; o.y += bi.y; o.z += bi.z; o.w += bi.w;
#pragma unroll
  for (int s = 0; s < 8; s++) {
    const float4 p = *(const float4*)&parts[(size_t)s * PSLICE + i4];
    o.x += p.x; o.y += p.y; o.z += p.z; o.w += p.w;
  }
  *(float4*)&xb[i4] = o;
  bf16x4 o16 = {(bf16)o.x, (bf16)o.y, (bf16)o.z, (bf16)o.w};
  *(bf16x4*)&xb16[i4] = o16;
}

// LN over 512 channels of (p0+p1 [+bias]); one wave/token, 4 tokens/block.
template <bool ENC>
__global__ __launch_bounds__(256) void ln_comb_k(
    const float* __restrict__ parts, const float* __restrict__ bias,
    const float* __restrict__ w, const float* __restrict__ b,
    const float* __restrict__ Wr, float* __restrict__ zout,
    float* __restrict__ out32, bf16* __restrict__ out16,
    float* __restrict__ probs) {
  const int wv = threadIdx.x >> 6, lane = threadIdx.x & 63;
  const int n = (blockIdx.x << 2) + wv;
  float v[8];
  float s = 0.f, s2 = 0.f;
#pragma unroll
  for (int i = 0; i < 8; i++) {
    const int c = (i << 6) + lane;
    float x = parts[(size_t)n * 512 + c] + parts[PSLICE + (size_t)n * 512 + c];
    if constexpr (ENC) x += bias[c];
    v[i] = x;
    s += x;
    s2 += x * x;
  }
#pragma unroll
  for (int off = 32; off > 0; off >>= 1) {
    s += __shfl_down(s, off);
    s2 += __shfl_down(s2, off);
  }
  s = __shfl(s, 0);
  s2 = __shfl(s2, 0);
  const float m = s * (1.f / 512.f);
  const float var = s2 * (1.f / 512.f) - m * m;
  const float r = rsqrtf(var + 1e-5f);
  float a0 = 0.f, a1 = 0.f, a2 = 0.f, a3 = 0.f;
#pragma unroll
  for (int i = 0; i < 8; i++) {
    const int c = (i << 6) + lane;
    const float o = (v[i] - m) * r * w[c] + b[c];
    if constexpr (ENC) {
      zout[(size_t)n * 512 + c] = v[i];
    } else {
      out32[(size_t)n * 512 + c] = o;
      a0 += o * Wr[c * 4 + 0];
      a1 += o * Wr[c * 4 + 1];
      a2 += o * Wr[c * 4 + 2];
      a3 += o * Wr[c * 4 + 3];
    }
    out16[(size_t)n * 512 + c] = (bf16)o;
  }
  if constexpr (!ENC) {
#pragma unroll
    for (int off = 32; off > 0; off >>= 1) {
      a0 += __shfl_down(a0, off);
      a1 += __shfl_down(a1, off);
      a2 += __shfl_down(a2, off);
      a3 += __shfl_down(a3, off);
    }
    if (lane == 0) {
      const float mx = fmaxf(fmaxf(a0, a1), fmaxf(a2, a3));
      const float e0 = expf(a0 - mx), e1 = expf(a1 - mx), e2 = expf(a2 - mx),
                  e3 = expf(a3 - mx);
      const float inv = 1.f / (e0 + e1 + e2 + e3);
      probs[n * 4 + 0] = e0 * inv;
      probs[n * 4 + 1] = e1 * inv;
      probs[n * 4 + 2] = e2 * inv;
      probs[n * 4 + 3] = e3 * inv;
    }
  }
}

// final residual v = xb + xn + sum(8 MoE2 partials).
// DO_LN: write z fp32 + LN(ln_sp next layer) -> znsp16.  else: z16 = bf16(v).
template <bool DO_LN>
__global__ __launch_bounds__(256) void addf2_k(
    const float* __restrict__ xb, const float* __restrict__ xn,
    const float* __restrict__ parts, const float* __restrict__ w,
    const float* __restrict__ b, float* __restrict__ zout,
    bf16* __restrict__ out16) {
  const int wv = threadIdx.x >> 6, lane = threadIdx.x & 63;
  const int n = (blockIdx.x << 2) + wv;
  float v[8];
  float s = 0.f, s2 = 0.f;
#pragma unroll
  for (int i = 0; i < 8; i++) {
    const size_t idx = (size_t)n * 512 + (i << 6) + lane;
    float x = xb[idx] + xn[idx];
#pragma unroll
    for (int sl = 0; sl < 8; sl++) x += parts[(size_t)sl * PSLICE + idx];
    v[i] = x;
    s += x;
    s2 += x * x;
  }
  if constexpr (!DO_LN) {
#pragma unroll
    for (int i = 0; i < 8; i++)
      out16[(size_t)n * 512 + (i << 6) + lane] = (bf16)v[i];
    return;
  }
#pragma unroll
  for (int off = 32; off > 0; off >>= 1) {
    s += __shfl_down(s, off);
    s2 += __shfl_down(s2, off);
  }
  s = __shfl(s, 0);
  s2 = __shfl(s2, 0);
  const float m = s * (1.f / 512.f);
  const float var = s2 * (1.f / 512.f) - m * m;
  const float r = rsqrtf(var + 1e-5f);
#pragma unroll
  for (int i = 0; i < 8; i++) {
    const int c = (i << 6) + lane;
    const float x = v[i];
    zout[(size_t)n * 512 + c] = x;
    out16[(size_t)n * 512 + c] = (bf16)((x - m) * r * w[c] + b[c]);
  }
}

// ---------- merged conversions: one launch, block-range decode ----------
__global__ __launch_bounds__(256) void cvt_all_k(
    const float* __restrict__ x, const float* __restrict__ Wenc,
    const float* __restrict__ Wdec, const float* __restrict__ W1,
    const float* __restrict__ W2, const float* __restrict__ E_re,
    const float* __restrict__ E_im, const float* __restrict__ Ed_re,
    const float* __restrict__ Ed_im, const float* __restrict__ conv_w,
    bf16* __restrict__ Ae, bf16* __restrict__ WencT, bf16* __restrict__ WdecT,
    bf16* __restrict__ W1T, bf16* __restrict__ W2Tc, bf16* __restrict__ MEt,
    bf16* __restrict__ convBt) {
  __shared__ float smem[4608];
  float(*tile)[33] = (float(*)[33])smem;
  const int tid = threadIdx.x;
  int b = blockIdx.x;
  const int tx = tid & 31, ty = tid >> 5;
  auto tpose = [&](const float* src, bf16* dst, int N, int dstride, int k0,
                   int n0) {
#pragma unroll
    for (int r = 0; r < 4; r++)
      tile[ty + 8 * r][tx] = src[(size_t)(k0 + ty + 8 * r) * N + n0 + tx];
    __syncthreads();
#pragma unroll
    for (int r = 0; r < 4; r++)
      dst[(size_t)(n0 + ty + 8 * r) * dstride + k0 + tx] =
          (bf16)tile[tx][ty + 8 * r];
  };
  if (b < 1024) {  // encoder patch gather + cast
    const int id = b * 256 + tid;
    const int n = id >> 7;
    const int kc = (id & 127) << 3;
    const int t = n >> 8, hp = (n >> 4) & 15, wp = n & 15;
    const int c = kc >> 8, ph = (kc >> 4) & 15, pw = kc & 15;
    const float* src =
        &x[(size_t)(((t * 4 + c) * 256 + hp * 16 + ph) << 8) + wp * 16 + pw];
    const float4 v0 = *(const float4*)src;
    const float4 v1 = *(const float4*)(src + 4);
    bf16* d = &Ae[(size_t)n * 1024 + kc];
    d[0] = (bf16)v0.x; d[1] = (bf16)v0.y; d[2] = (bf16)v0.z; d[3] = (bf16)v0.w;
    d[4] = (bf16)v1.x; d[5] = (bf16)v1.y; d[6] = (bf16)v1.z; d[7] = (bf16)v1.w;
    return;
  }
  b -= 1024;
  if (b < 512) {
    tpose(Wenc, WencT, 512, 1024, (b & 31) * 32, (b >> 5) * 32);
    return;
  }
  b -= 512;
  if (b < 512) {
    tpose(Wdec, WdecT, 1024, 512, (b & 15) * 32, (b >> 4) * 32);
    return;
  }
  b -= 512;
  if (b < 4096) {
    const int z = b >> 9, rem = b & 511;
    tpose(W1 + (size_t)z * 524288, W1T + (size_t)z * 524288, 1024, 512,
          (rem & 15) * 32, (rem >> 4) * 32);
    return;
  }
  b -= 4096;
  if (b < 4096) {
    const int z = b >> 9, rem = b & 511;
    const int l = z >> 2, e = z & 3;
    tpose(W2 + (size_t)z * 524288, W2Tc + (size_t)l * 2097152 + e * 1024, 512,
          4096, (rem & 31) * 32, (rem >> 5) * 32);
    return;
  }
  b -= 4096;
  if (b < 4096) {
    const int z = b >> 10;
    const int l = z >> 1, which = z & 1;
    const float* Er = (which ? Ed_re : E_re) + l * 65536;
    const float* Ei = (which ? Ed_im : E_im) + l * 65536;
    bf16* dst = MEt + (size_t)z * 262144;
    const int idx = (b & 1023) * 256 + tid;
    const int j = idx >> 9, k = idx & 511;
    const int kk = k & 255, jj = j & 255;
    const float er = Er[kk * 256 + jj], ei = Ei[kk * 256 + jj];
    const float v = (k < 256) ? ((j < 256) ? er : ei) : ((j < 256) ? -ei : er);
    dst[idx] = (bf16)v;
    return;
  }
  b -= 4096;
  {  // conv_w: one block per (l,co); coalesced read -> LDS -> coalesced write
    const int l = b >> 9, co = b & 511;
    const float* src = conv_w + (size_t)l * 2359296 + (size_t)co * 4608;
    bf16* d = convBt + (size_t)l * 2359296 + (size_t)co * 4608;
    for (int i = tid; i < 4608; i += 256) smem[i] = src[i];
    __syncthreads();
    for (int o = tid; o < 4608; o += 256) {
      const int s = o >> 9, ci = o & 511;
      d[o] = (bf16)smem[ci * 9 + s];
    }
  }
}

// Parallel src/gate from precomputed xmean sums. grid (8 t, 3 part) x 256.
__global__ __launch_bounds__(256) void srcgate_k(
    const float* __restrict__ xmean, const float* __restrict__ Wsr,
    const float* __restrict__ Wsi, const float* __restrict__ Wg,
    const float* __restrict__ bg, float* __restrict__ srcs,
    float* __restrict__ gts) {
  const int t = blockIdx.x, part = blockIdx.y, d = threadIdx.x;
  __shared__ float sxm[512];
  for (int c = d; c < 512; c += 256) sxm[c] = xmean[t * 512 + c] * (1.f / 256.f);
  __syncthreads();
  if (part == 0) {
    float s0 = 0.f, s1 = 0.f, s2 = 0.f, s3 = 0.f;
#pragma unroll 4
    for (int e = 0; e < 256; e += 4) {
      s0 += sxm[e + 0] * Wsr[(e + 0) * 256 + d] - sxm[256 + e + 0] * Wsi[(e + 0) * 256 + d];
      s1 += sxm[e + 1] * Wsr[(e + 1) * 256 + d] - sxm[256 + e + 1] * Wsi[(e + 1) * 256 + d];
      s2 += sxm[e + 2] * Wsr[(e + 2) * 256 + d] - sxm[256 + e + 2] * Wsi[(e + 2) * 256 + d];
      s3 += sxm[e + 3] * Wsr[(e + 3) * 256 + d] - sxm[256 + e + 3] * Wsi[(e + 3) * 256 + d];
    }
    srcs[t * 512 + d] = (s0 + s1) + (s2 + s3);
  } else if (part == 1) {
    float s0 = 0.f, s1 = 0.f, s2 = 0.f, s3 = 0.f;
#pragma unroll 4
    for (int e = 0; e < 256; e += 4) {
      s0 += sxm[e + 0] * Wsi[(e + 0) * 256 + d] + sxm[256 + e + 0] * Wsr[(e + 0) * 256 + d];
      s1 += sxm[e + 1] * Wsi[(e + 1) * 256 + d] + sxm[256 + e + 1] * Wsr[(e + 1) * 256 + d];
      s2 += sxm[e + 2] * Wsi[(e + 2) * 256 + d] + sxm[256 + e + 2] * Wsr[(e + 2) * 256 + d];
      s3 += sxm[e + 3] * Wsi[(e + 3) * 256 + d] + sxm[256 + e + 3] * Wsr[(e + 3) * 256 + d];
    }
    srcs[t * 512 + 256 + d] = (s0 + s1) + (s2 + s3);
  } else {
    float s0 = 0.f, s1 = 0.f, s2 = 0.f, s3 = 0.f;
#pragma unroll 4
    for (int c = 0; c < 512; c += 4) {
      s0 += sxm[c + 0] * Wg[(c + 0) * 256 + d];
      s1 += sxm[c + 1] * Wg[(c + 1) * 256 + d];
      s2 += sxm[c + 2] * Wg[(c + 2) * 256 + d];
      s3 += sxm[c + 3] * Wg[(c + 3) * 256 + d];
    }
    const float ga = (s0 + s1) + (s2 + s3) + bg[d];
    gts[t * 256 + d] = 1.f / (1.f + expf(-ga));
  }
}

// Per-(p,d) time scan over esq1 partials (2 slices); opd/opf inline.
template <bool FIRST>
__global__ __launch_bounds__(256) void time_scan_k(
    const float* __restrict__ parts, const float* __restrict__ gts,
    const float* __restrict__ srcs, const float* __restrict__ lamre,
    const float* __restrict__ lamim, const float* __restrict__ dt,
    bf16* __restrict__ hout16, float* __restrict__ hprev) {
  const int d = threadIdx.x;
  const int p = blockIdx.x;
  const float lr0 = lamre[d];
  const float sp = (lr0 > 20.f) ? lr0 : log1pf(expf(lr0));
  const float lre = -(sp + 0.01f);
  const float lim = lamim[d];
  const float den = lre * lre + lim * lim;
  float ar[8], ai[8], ofr[8], ofi[8];
#pragma unroll
  for (int t = 0; t < 8; t++) {
    const float dtv = dt[t];
    const float er = expf(lre * dtv);
    const float odr = er * cosf(lim * dtv);
    const float odi = er * sinf(lim * dtv);
    ar[t] = odr;
    ai[t] = odi;
    const float nr = odr - 1.f, ni = odi;
    ofr[t] = (nr * lre + ni * lim) / den;
    ofi[t] = (ni * lre - nr * lim) / den;
  }
  float hr = 0.f, hi = 0.f;
  float hpr = 0.f, hpi = 0.f;
  if constexpr (!FIRST) {
    hpr = hprev[p * 512 + d];
    hpi = hprev[p * 512 + 256 + d];
  }
  float o7r = 0.f, o7i = 0.f;
#pragma unroll
  for (int t = 0; t < 8; t++) {
    const size_t base = (size_t)((t << 8) + p) * 512;
    const float xr = parts[base + d] + parts[PSLICE + base + d];
    const float xi = parts[base + 256 + d] + parts[PSLICE + base + 256 + d];
    const float g = gts[t * 256 + d];
    const float sr = srcs[t * 512 + d], si = srcs[t * 512 + 256 + d];
    const float fr = xr * g + sr * (1.f - g);
    const float fi = xi * g + si * (1.f - g);
    const float ur = fr * ofr[t] - fi * ofi[t];
    const float ui = fr * ofi[t] + fi * ofr[t];
    const float nhr = ur + ar[t] * hr - ai[t] * hi;
    const float nhi = ui + ar[t] * hi + ai[t] * hr;
    hr = nhr;
    hi = nhi;
    const float outr = hr + ar[t] * hpr - ai[t] * hpi;
    const float outi = hi + ar[t] * hpi + ai[t] * hpr;
    hout16[base + d] = (bf16)outr;
    hout16[base + 256 + d] = (bf16)outi;
    if (t == 7) {
      o7r = outr;
      o7i = outi;
    }
  }
  hprev[p * 512 + d] = o7r;
  hprev[p * 512 + 256 + d] = o7i;
}

extern "C" void kernel_launch(void* const* d_in, const int* in_sizes, int n_in,
                              void* d_out, int out_size, void* d_ws,
                              size_t ws_size, hipStream_t stream) {
  const float* x_in = (const float*)d_in[0];
  const float* dt = (const float*)d_in[1];
  const float* Wenc = (const float*)d_in[2];
  const float* benc = (const float*)d_in[3];
  const float* Wdec = (const float*)d_in[4];
  const float* bdec = (const float*)d_in[5];
  const float* ln_sp_w = (const float*)d_in[6];
  const float* ln_sp_b = (const float*)d_in[7];
  const float* conv_w = (const float*)d_in[8];
  const float* conv_b = (const float*)d_in[9];
  const float* E_re = (const float*)d_in[10];
  const float* E_im = (const float*)d_in[11];
  const float* Ed_re = (const float*)d_in[12];
  const float* Ed_im = (const float*)d_in[13];
  const float* Ws_re = (const float*)d_in[14];
  const float* Ws_im = (const float*)d_in[15];
  const float* Wg = (const float*)d_in[16];
  const float* bg = (const float*)d_in[17];
  const float* lam_re = (const float*)d_in[18];
  const float* lam_im = (const float*)d_in[19];
  const float* ln_t_w = (const float*)d_in[20];
  const float* ln_t_b = (const float*)d_in[21];
  const float* Wr = (const float*)d_in[22];
  const float* W1 = (const float*)d_in[23];
  const float* W2 = (const float*)d_in[24];
  float* out = (float*)d_out;

  float* ws = (float*)d_ws;
  size_t off = 0;
  auto allocf = [&](size_t n) {
    float* p = ws + off;
    off += n;
    return p;
  };
  auto allocb = [&](size_t n) {
    bf16* p = (bf16*)(ws + off);
    off += n / 2;
    return p;
  };
  float* z = allocf((size_t)TOKS * 512);
  float* xn = allocf((size_t)TOKS * 512);
  float* xb = allocf((size_t)TOKS * 512);
  float* parts = allocf((size_t)8 * PSLICE);
  float* hprev = allocf(256 * 512);
  float* xm = allocf(8 * 512);
  float* srcs = allocf(8 * 512);
  float* gts = allocf(8 * 256);
  float* probs = allocf((size_t)TOKS * 4);
  bf16* znsp16 = allocb((size_t)TOKS * 512);
  bf16* xn16 = allocb((size_t)TOKS * 512);
  bf16* xb16 = allocb((size_t)TOKS * 512);
  bf16* z16 = allocb((size_t)TOKS * 512);
  bf16* hb16 = allocb((size_t)TOKS * 512);
  bf16* hid16 = allocb((size_t)TOKS * 4096);
  bf16* Aenc16 = allocb((size_t)TOKS * 1024);
  bf16* WencT = allocb((size_t)512 * 1024);
  bf16* WdecT = allocb((size_t)1024 * 512);
  bf16* MEt = allocb((size_t)4 * 512 * 512);
  bf16* convBt = allocb((size_t)2 * 512 * 4608);
  bf16* W1T = allocb((size_t)8 * 1024 * 512);
  bf16* W2Tc = allocb((size_t)2 * 512 * 4096);

  // ---- all conversions in one launch ----
  cvt_all_k<<<15360, 256, 0, stream>>>(x_in, Wenc, Wdec, W1, W2, E_re, E_im,
                                       Ed_re, Ed_im, conv_w, Aenc16, WencT,
                                       WdecT, W1T, W2Tc, MEt, convBt);

  // ---- encoder: split-K=2, combine folded into LN ----
  mgemm_k<EENC, 2><<<dim3(32, 8, 2), 256, 0, stream>>>(
      Aenc16, WencT, nullptr, nullptr, nullptr, nullptr, parts, nullptr, 1024,
      512);
  ln_comb_k<true><<<512, 256, 0, stream>>>(parts, benc, ln_sp_w, ln_sp_b,
                                           nullptr, z, nullptr, znsp16,
                                           nullptr);

  for (int l = 0; l < 2; l++) {
    mgemm_k<ECONV, 8><<<dim3(32, 8, 8), 256, 0, stream>>>(
        znsp16, convBt + (size_t)l * 2359296, nullptr, nullptr, nullptr,
        nullptr, parts, nullptr, 4608, 512);
    conv_ep_k<<<1024, 256, 0, stream>>>(parts, conv_b + l * 512, z, xb, xb16,
                                        xm);
    mgemm_k<ESQM, 2><<<dim3(32, 8, 2), 256, 0, stream>>>(
        xb16, MEt + (size_t)(l * 2) * 262144, nullptr, nullptr, nullptr,
        nullptr, parts, xm, 512, 512);
    srcgate_k<<<dim3(8, 3), 256, 0, stream>>>(xm, Ws_re + l * 65536,
                                              Ws_im + l * 65536,
                                              Wg + l * 131072, bg + l * 256,
                                              srcs, gts);
    if (l == 0)
      time_scan_k<true><<<256, 256, 0, stream>>>(parts, gts, srcs, lam_re,
                                                 lam_im, dt, hb16, hprev);
    else
      time_scan_k<false><<<256, 256, 0, stream>>>(parts, gts, srcs,
                                                  lam_re + 256, lam_im + 256,
                                                  dt, hb16, hprev);
    mgemm_k<ESQ, 2><<<dim3(32, 8, 2), 256, 0, stream>>>(
        hb16, MEt + (size_t)(l * 2 + 1) * 262144, nullptr, nullptr, nullptr,
        nullptr, parts, nullptr, 512, 512);
    ln_comb_k<false><<<512, 256, 0, stream>>>(parts, nullptr, ln_t_w + l * 512,
                                              ln_t_b + l * 512, Wr + l * 2048,
                                              nullptr, xn, xn16, probs);
    mgemm_k<EMOE1, 1><<<dim3(32, 16, 4), 256, 0, stream>>>(
        xn16, W1T + (size_t)l * 2097152, nullptr, probs, nullptr, hid16,
        nullptr, nullptr, 512, 1024);
    mgemm_k<EMOE2, 8><<<dim3(32, 8, 8), 256, 0, stream>>>(
        hid16, W2Tc + (size_t)l * 2097152, nullptr, nullptr, nullptr, nullptr,
        parts, nullptr, 4096, 512);
    if (l == 0)
      addf2_k<true><<<512, 256, 0, stream>>>(xb, xn, parts, ln_sp_w + 512,
                                             ln_sp_b + 512, z, znsp16);
    else
      addf2_k<false><<<512, 256, 0, stream>>>(xb, xn, parts, nullptr, nullptr,
                                              nullptr, z16);
  }

  // ---- decoder ----
  mgemm_k<EDEC, 1><<<dim3(32, 16), 256, 0, stream>>>(
      z16, WdecT, bdec, nullptr, out, nullptr, nullptr, nullptr, 512, 1024);
}